// Round 1
// baseline (1417.050 us; speedup 1.0000x reference)
//
#include <hip/hip_runtime.h>

typedef __attribute__((ext_vector_type(8))) __bf16 bf16x8;
typedef __attribute__((ext_vector_type(8))) unsigned short u16x8;
typedef __attribute__((ext_vector_type(4))) float f32x4;
typedef unsigned short u16;

#define TSEQ 2064   /* 16 groups * 129 tokens (incl relay) per batch */
#define NTOK 4128   /* 2 batches * TSEQ */

__device__ __forceinline__ float bf2f(u16 u) {
  unsigned x = ((unsigned)u) << 16;
  return __builtin_bit_cast(float, x);
}
__device__ __forceinline__ u16 f2bf(float f) {
  unsigned u = __builtin_bit_cast(unsigned, f);
  u += 0x7fffu + ((u >> 16) & 1u);     // round-to-nearest-even
  return (u16)(u >> 16);
}

// ---------------- weight transpose + f32->bf16 cast: (L,K,N) -> (L,N,K) ----
__global__ __launch_bounds__(256) void transpose_w(const float* __restrict__ src,
                                                   u16* __restrict__ dst,
                                                   int K, int N)
{
  __shared__ float tile[32][33];
  const int l = blockIdx.z;
  src += (size_t)l * K * N;
  dst += (size_t)l * K * N;
  const int n0 = blockIdx.x * 32, k0 = blockIdx.y * 32;
  const int c = threadIdx.x & 31, r = threadIdx.x >> 5;   // r in 0..7
#pragma unroll
  for (int rr = r; rr < 32; rr += 8)
    tile[rr][c] = src[(size_t)(k0 + rr) * N + n0 + c];
  __syncthreads();
#pragma unroll
  for (int rr = r; rr < 32; rr += 8)
    dst[(size_t)(n0 + rr) * K + k0 + c] = f2bf(tile[c][rr]);
}

// ---------------- assemble working sequence with relay tokens --------------
__global__ void build_x(const float* __restrict__ xin, const float* __restrict__ relay,
                        float* __restrict__ xw)
{
  const int total = 2 * TSEQ * 512;
  for (int idx = blockIdx.x * 256 + threadIdx.x; idx < total; idx += gridDim.x * 256) {
    int col = idx & 511;
    int tok = (idx >> 9) % TSEQ;
    int b   = idx / (TSEQ * 512);
    int g = tok / 129, s = tok % 129;
    float v = (s == 0) ? relay[col]
                       : xin[((size_t)b * 2048 + g * 128 + (s - 1)) * 512 + col];
    xw[idx] = v;
  }
}

__global__ void extract_out(const float* __restrict__ xw, float* __restrict__ out)
{
  const int total = 2 * 2048 * 512;
  for (int idx = blockIdx.x * 256 + threadIdx.x; idx < total; idx += gridDim.x * 256) {
    int col = idx & 511;
    int tok = (idx >> 9) & 2047;
    int b   = idx / (2048 * 512);
    int g = tok >> 7, s = tok & 127;
    out[idx] = xw[((size_t)b * TSEQ + g * 129 + s + 1) * 512 + col];
  }
}

// ---------------- layernorm: f32 in -> bf16 out ----------------------------
__global__ __launch_bounds__(256) void ln_kernel(const float* __restrict__ x,
                                                 const float* __restrict__ g,
                                                 const float* __restrict__ bta,
                                                 u16* __restrict__ y, int M)
{
  const int wid = threadIdx.x >> 6, lane = threadIdx.x & 63;
  const int row = blockIdx.x * 4 + wid;
  if (row >= M) return;
  const float* xr = x + (size_t)row * 512;
  float v[8];
  float s = 0.f;
#pragma unroll
  for (int j = 0; j < 8; ++j) { v[j] = xr[j * 64 + lane]; s += v[j]; }
#pragma unroll
  for (int m = 1; m <= 32; m <<= 1) s += __shfl_xor(s, m);
  float mean = s * (1.f / 512.f);
  float vs = 0.f;
#pragma unroll
  for (int j = 0; j < 8; ++j) { float d = v[j] - mean; vs += d * d; }
#pragma unroll
  for (int m = 1; m <= 32; m <<= 1) vs += __shfl_xor(vs, m);
  float rstd = rsqrtf(vs * (1.f / 512.f) + 1e-5f);
  u16* yr = y + (size_t)row * 512;
#pragma unroll
  for (int j = 0; j < 8; ++j) {
    int c = j * 64 + lane;
    yr[c] = f2bf((v[j] - mean) * rstd * g[c] + bta[c]);
  }
}

// ---------------- generic bf16 MFMA GEMM: C = A(MxK) * Bt(NxK)^T -----------
// 128x128 tile, 4 waves (2x2), each wave 64x64 via 4x4 16x16x32 fragments.
template<bool HAS_BIAS, bool ACT, bool RESID, bool OUT_BF16>
__global__ __launch_bounds__(256) void gemm_bf16(
    const u16* __restrict__ A, const u16* __restrict__ Bt,
    const float* __restrict__ bias, const float* __restrict__ resid,
    void* __restrict__ outp, int M, int N, int K)
{
  __shared__ __attribute__((aligned(16))) u16 As[128][40];
  __shared__ __attribute__((aligned(16))) u16 Bs[128][40];
  const int tid = threadIdx.x;
  const int lane = tid & 63, wid = tid >> 6;
  const int row0 = blockIdx.x * 128, col0 = blockIdx.y * 128;
  const int wm = (wid >> 1) * 64, wn = (wid & 1) * 64;
  f32x4 acc[4][4];
#pragma unroll
  for (int m = 0; m < 4; ++m)
#pragma unroll
    for (int n = 0; n < 4; ++n) acc[m][n] = (f32x4)0.f;
  const int seg = tid & 3, r = tid >> 2;          // staging: 4 x 16B per row
  const int fr = lane & 15, fk = (lane >> 4) * 8; // fragment addressing

  for (int k0 = 0; k0 < K; k0 += 32) {
    __syncthreads();
#pragma unroll
    for (int rr = r; rr < 128; rr += 64) {
      int ga = row0 + rr;
      u16x8 av = (u16x8)0;
      if (ga < M) av = *(const u16x8*)&A[(size_t)ga * K + k0 + seg * 8];
      *(u16x8*)&As[rr][seg * 8] = av;
      int gb = col0 + rr;   // N is always a multiple of 128 here
      u16x8 bv = *(const u16x8*)&Bt[(size_t)gb * K + k0 + seg * 8];
      *(u16x8*)&Bs[rr][seg * 8] = bv;
    }
    __syncthreads();
    bf16x8 a[4], b[4];
#pragma unroll
    for (int m = 0; m < 4; ++m) a[m] = *(const bf16x8*)&As[wm + m * 16 + fr][fk];
#pragma unroll
    for (int n = 0; n < 4; ++n) b[n] = *(const bf16x8*)&Bs[wn + n * 16 + fr][fk];
#pragma unroll
    for (int m = 0; m < 4; ++m)
#pragma unroll
      for (int n = 0; n < 4; ++n)
        acc[m][n] = __builtin_amdgcn_mfma_f32_16x16x32_bf16(a[m], b[n], acc[m][n], 0, 0, 0);
  }

  const int fg = lane >> 4;
#pragma unroll
  for (int m = 0; m < 4; ++m) {
#pragma unroll
    for (int n = 0; n < 4; ++n) {
#pragma unroll
      for (int j = 0; j < 4; ++j) {
        int grow = row0 + wm + m * 16 + fg * 4 + j;
        int gcol = col0 + wn + n * 16 + fr;
        if (grow < M) {
          float v = acc[m][n][j];
          if (HAS_BIAS) v += bias[gcol];
          if (ACT) v = (v > 0.f) ? v : 0.01f * v;
          if (RESID) v += resid[(size_t)grow * N + gcol];
          if (OUT_BF16) ((u16*)outp)[(size_t)grow * N + gcol] = f2bf(v);
          else ((float*)outp)[(size_t)grow * N + gcol] = v;
        }
      }
    }
  }
}

// ---------------- flash attention over the 2064-token sequence -------------
// grid (33 q-tiles, b*h=16); block 256 = 4 waves; BQ=64 (16 rows/wave), BKV=64.
__global__ __launch_bounds__(256) void flash_attn(const u16* __restrict__ qkv,
                                                  u16* __restrict__ ob)
{
  const int qt = blockIdx.x;
  const int b = blockIdx.y >> 3, h = blockIdx.y & 7;
  const int tid = threadIdx.x, lane = tid & 63, wid = tid >> 6;
  __shared__ __attribute__((aligned(16))) u16 Qs[64][72];
  __shared__ __attribute__((aligned(16))) u16 Ks[64][72];
  __shared__ __attribute__((aligned(16))) u16 Vt[64][72];   // [dh][key]
  __shared__ __attribute__((aligned(16))) u16 Ps[4][16][72];
  const int q0 = qt * 64;
  const int seg = tid & 7, r = tid >> 3;   // 8 x 16B segments per 64-row tile

#pragma unroll
  for (int rr = r; rr < 64; rr += 32) {
    int tok = q0 + rr;
    u16x8 v = (u16x8)0;
    if (tok < TSEQ) v = *(const u16x8*)&qkv[((size_t)(b * TSEQ + tok)) * 1536 + h * 64 + seg * 8];
    *(u16x8*)&Qs[rr][seg * 8] = v;
  }
  __syncthreads();
  const int fr = lane & 15, fk = (lane >> 4) * 8;
  bf16x8 aq0 = *(const bf16x8*)&Qs[wid * 16 + fr][fk];
  bf16x8 aq1 = *(const bf16x8*)&Qs[wid * 16 + fr][32 + fk];

  f32x4 oacc[4];
#pragma unroll
  for (int nf = 0; nf < 4; ++nf) oacc[nf] = (f32x4)0.f;
  float mrow[4] = {-1e30f, -1e30f, -1e30f, -1e30f};
  float lsum[4] = {0.f, 0.f, 0.f, 0.f};

  for (int kt = 0; kt < 33; ++kt) {
    __syncthreads();
#pragma unroll
    for (int rr = r; rr < 64; rr += 32) {
      int tok = kt * 64 + rr;
      u16x8 kv = (u16x8)0, vv = (u16x8)0;
      if (tok < TSEQ) {
        size_t base = ((size_t)(b * TSEQ + tok)) * 1536 + h * 64 + seg * 8;
        kv = *(const u16x8*)&qkv[base + 512];
        vv = *(const u16x8*)&qkv[base + 1024];
      }
      *(u16x8*)&Ks[rr][seg * 8] = kv;
#pragma unroll
      for (int j = 0; j < 8; ++j) Vt[seg * 8 + j][rr] = vv[j];  // transpose V
    }
    __syncthreads();

    f32x4 s[4];
#pragma unroll
    for (int n = 0; n < 4; ++n) {
      bf16x8 bk0 = *(const bf16x8*)&Ks[n * 16 + fr][fk];
      bf16x8 bk1 = *(const bf16x8*)&Ks[n * 16 + fr][32 + fk];
      f32x4 t = (f32x4)0.f;
      t = __builtin_amdgcn_mfma_f32_16x16x32_bf16(aq0, bk0, t, 0, 0, 0);
      t = __builtin_amdgcn_mfma_f32_16x16x32_bf16(aq1, bk1, t, 0, 0, 0);
      s[n] = t;
    }
#pragma unroll
    for (int n = 0; n < 4; ++n) {
      bool valid = (kt * 64 + n * 16 + fr) < TSEQ;
#pragma unroll
      for (int j = 0; j < 4; ++j) s[n][j] = valid ? s[n][j] * 0.125f : -1e30f;
    }
    float sc[4];
#pragma unroll
    for (int j = 0; j < 4; ++j) {
      float m0 = fmaxf(fmaxf(s[0][j], s[1][j]), fmaxf(s[2][j], s[3][j]));
#pragma unroll
      for (int d = 1; d <= 8; d <<= 1) m0 = fmaxf(m0, __shfl_xor(m0, d));
      float nm = fmaxf(mrow[j], m0);
      sc[j] = __expf(mrow[j] - nm);
      mrow[j] = nm;
      lsum[j] *= sc[j];
    }
#pragma unroll
    for (int nf = 0; nf < 4; ++nf)
#pragma unroll
      for (int j = 0; j < 4; ++j) oacc[nf][j] *= sc[j];

    float ps[4] = {0.f, 0.f, 0.f, 0.f};
#pragma unroll
    for (int n = 0; n < 4; ++n) {
#pragma unroll
      for (int j = 0; j < 4; ++j) {
        float p = __expf(s[n][j] - mrow[j]);
        ps[j] += p;
        Ps[wid][(lane >> 4) * 4 + j][n * 16 + fr] = f2bf(p);
      }
    }
#pragma unroll
    for (int j = 0; j < 4; ++j) {
      float t = ps[j];
#pragma unroll
      for (int d = 1; d <= 8; d <<= 1) t += __shfl_xor(t, d);
      lsum[j] += t;
    }
#pragma unroll
    for (int kc = 0; kc < 2; ++kc) {
      bf16x8 ap = *(const bf16x8*)&Ps[wid][fr][kc * 32 + fk];
#pragma unroll
      for (int nf = 0; nf < 4; ++nf) {
        bf16x8 bv = *(const bf16x8*)&Vt[nf * 16 + fr][kc * 32 + fk];
        oacc[nf] = __builtin_amdgcn_mfma_f32_16x16x32_bf16(ap, bv, oacc[nf], 0, 0, 0);
      }
    }
  }

  float inv[4];
#pragma unroll
  for (int j = 0; j < 4; ++j) inv[j] = 1.f / lsum[j];
#pragma unroll
  for (int nf = 0; nf < 4; ++nf) {
#pragma unroll
    for (int j = 0; j < 4; ++j) {
      int row = q0 + wid * 16 + (lane >> 4) * 4 + j;
      if (row < TSEQ)
        ob[((size_t)(b * TSEQ + row)) * 512 + h * 64 + nf * 16 + fr] = f2bf(oacc[nf][j] * inv[j]);
    }
  }
}

// ---------------- relay-token global attention (32 tokens total) -----------
__global__ __launch_bounds__(256) void global_attn(const u16* __restrict__ rqkv,
                                                   u16* __restrict__ ro)
{
  const int b = blockIdx.x >> 3, h = blockIdx.x & 7;
  __shared__ float q[16][64], k[16][64], v[16][64], s[16][16], p[16][16];
  const int tid = threadIdx.x;
  for (int idx = tid; idx < 1024; idx += 256) {
    int rr = idx >> 6, c = idx & 63;
    size_t base = (size_t)(b * 16 + rr) * 1536 + h * 64 + c;
    q[rr][c] = bf2f(rqkv[base]);
    k[rr][c] = bf2f(rqkv[base + 512]);
    v[rr][c] = bf2f(rqkv[base + 1024]);
  }
  __syncthreads();
  {
    int i = tid >> 4, j = tid & 15;
    float acc = 0.f;
#pragma unroll
    for (int d = 0; d < 64; ++d) acc += q[i][d] * k[j][d];
    s[i][j] = acc * 0.125f;
  }
  __syncthreads();
  if (tid < 16) {
    float mx = -1e30f;
#pragma unroll
    for (int j = 0; j < 16; ++j) mx = fmaxf(mx, s[tid][j]);
    float sum = 0.f;
#pragma unroll
    for (int j = 0; j < 16; ++j) { float e = __expf(s[tid][j] - mx); p[tid][j] = e; sum += e; }
    float iv = 1.f / sum;
#pragma unroll
    for (int j = 0; j < 16; ++j) p[tid][j] *= iv;
  }
  __syncthreads();
  for (int idx = tid; idx < 1024; idx += 256) {
    int rr = idx >> 6, c = idx & 63;
    float acc = 0.f;
#pragma unroll
    for (int j = 0; j < 16; ++j) acc += p[rr][j] * v[j][c];
    ro[(size_t)(b * 16 + rr) * 512 + h * 64 + c] = f2bf(acc);
  }
}

__global__ void gather_relay(const u16* __restrict__ y, u16* __restrict__ rbuf)
{
  int idx = blockIdx.x * 256 + threadIdx.x;   // 32*512
  int col = idx & 511, rr = idx >> 9;
  int b = rr >> 4, g = rr & 15;
  rbuf[idx] = y[((size_t)b * TSEQ + g * 129) * 512 + col];
}

__global__ void relay_scatter(const float* __restrict__ rout, const u16* __restrict__ rbuf,
                              u16* __restrict__ y)
{
  int idx = blockIdx.x * 256 + threadIdx.x;   // 32*512
  int col = idx & 511, rr = idx >> 9;
  int b = rr >> 4, g = rr & 15;
  y[((size_t)b * TSEQ + g * 129) * 512 + col] = f2bf(rout[idx] + bf2f(rbuf[idx]));
}

// ---------------------------------------------------------------------------
extern "C" void kernel_launch(void* const* d_in, const int* in_sizes, int n_in,
                              void* d_out, int out_size, void* d_ws, size_t ws_size,
                              hipStream_t stream)
{
  const float* x_in     = (const float*)d_in[0];
  const float* rel_emb  = (const float*)d_in[1];
  const float* ln1_g    = (const float*)d_in[2];
  const float* ln1_b    = (const float*)d_in[3];
  const float* loc_qkv  = (const float*)d_in[4];
  const float* loc_ow   = (const float*)d_in[5];
  const float* loc_ob   = (const float*)d_in[6];
  const float* glob_qkv = (const float*)d_in[7];
  const float* glob_ow  = (const float*)d_in[8];
  const float* glob_ob  = (const float*)d_in[9];
  const float* ln2_g    = (const float*)d_in[10];
  const float* ln2_b    = (const float*)d_in[11];
  const float* ff_w1    = (const float*)d_in[12];
  const float* ff_b1    = (const float*)d_in[13];
  const float* ff_w2    = (const float*)d_in[14];
  const float* ff_b2    = (const float*)d_in[15];

  char* ws = (char*)d_ws;                      // ~67.6 MB used
  float* xbuf = (float*)(ws + 0);              // f32 4128x512
  u16*   ybuf = (u16*)(ws + 8454144);          // bf16 4128x512 (LN out, reused)
  u16*   obuf = (u16*)(ws + 12681216);         // bf16 4128x512 (attn out)
  u16*   big  = (u16*)(ws + 16908288);         // bf16 4128x2048 (qkv / ffn hidden)
  u16*   wLQ  = (u16*)(ws + 33816576);         // 4x1536x512
  u16*   wGQ  = (u16*)(ws + 40108032);
  u16*   wLO  = (u16*)(ws + 46399488);         // 4x512x512
  u16*   wGO  = (u16*)(ws + 48496640);
  u16*   wF1  = (u16*)(ws + 50593792);         // 4x2048x512
  u16*   wF2  = (u16*)(ws + 58982400);         // 4x512x2048
  u16*   rbuf = (u16*)(ws + 67371008);         // 32x512
  u16*   rqkv = (u16*)(ws + 67403776);         // 32x1536
  u16*   rov  = (u16*)(ws + 67502080);         // 32x512
  float* rout = (float*)(ws + 67534848);       // 32x512 f32

  dim3 B(256);
  transpose_w<<<dim3(48, 16, 4), B, 0, stream>>>(loc_qkv, wLQ, 512, 1536);
  transpose_w<<<dim3(48, 16, 4), B, 0, stream>>>(glob_qkv, wGQ, 512, 1536);
  transpose_w<<<dim3(16, 16, 4), B, 0, stream>>>(loc_ow, wLO, 512, 512);
  transpose_w<<<dim3(16, 16, 4), B, 0, stream>>>(glob_ow, wGO, 512, 512);
  transpose_w<<<dim3(64, 16, 4), B, 0, stream>>>(ff_w1, wF1, 512, 2048);
  transpose_w<<<dim3(16, 64, 4), B, 0, stream>>>(ff_w2, wF2, 2048, 512);

  build_x<<<8256, B, 0, stream>>>(x_in, rel_emb, xbuf);

  for (int l = 0; l < 4; ++l) {
    ln_kernel<<<1032, B, 0, stream>>>(xbuf, ln1_g + l * 512, ln1_b + l * 512, ybuf, NTOK);
    if (l + 1 >= 2) {
      gather_relay<<<64, B, 0, stream>>>(ybuf, rbuf);
      gemm_bf16<false, false, false, true><<<dim3(1, 12), B, 0, stream>>>(
          rbuf, wGQ + (size_t)l * 1536 * 512, nullptr, nullptr, rqkv, 32, 1536, 512);
      global_attn<<<16, B, 0, stream>>>(rqkv, rov);
      gemm_bf16<true, false, false, false><<<dim3(1, 4), B, 0, stream>>>(
          rov, wGO + (size_t)l * 512 * 512, glob_ob + l * 512, nullptr, rout, 32, 512, 512);
      relay_scatter<<<64, B, 0, stream>>>(rout, rbuf, ybuf);
    }
    gemm_bf16<false, false, false, true><<<dim3(33, 12), B, 0, stream>>>(
        ybuf, wLQ + (size_t)l * 1536 * 512, nullptr, nullptr, big, NTOK, 1536, 512);
    flash_attn<<<dim3(33, 16), B, 0, stream>>>(big, obuf);
    gemm_bf16<true, false, true, false><<<dim3(33, 4), B, 0, stream>>>(
        obuf, wLO + (size_t)l * 512 * 512, loc_ob + l * 512, xbuf, xbuf, NTOK, 512, 512);
    ln_kernel<<<1032, B, 0, stream>>>(xbuf, ln2_g + l * 512, ln2_b + l * 512, ybuf, NTOK);
    gemm_bf16<true, true, false, true><<<dim3(33, 16), B, 0, stream>>>(
        ybuf, wF1 + (size_t)l * 2048 * 512, ff_b1 + l * 2048, nullptr, big, NTOK, 2048, 512);
    gemm_bf16<true, false, true, false><<<dim3(33, 4), B, 0, stream>>>(
        big, wF2 + (size_t)l * 512 * 2048, ff_b2 + l * 512, xbuf, xbuf, NTOK, 512, 2048);
  }
  extract_out<<<8192, B, 0, stream>>>(xbuf, (float*)d_out);
}

// Round 3
// 1159.902 us; speedup vs baseline: 1.2217x; 1.2217x over previous
//
#include <hip/hip_runtime.h>

typedef __attribute__((ext_vector_type(8))) __bf16 bf16x8;
typedef __attribute__((ext_vector_type(8))) unsigned short u16x8;
typedef __attribute__((ext_vector_type(4))) float f32x4;
typedef unsigned short u16;

#define TSEQ 2064   /* 16 groups * 129 tokens (incl relay) per batch */
#define NTOK 4128   /* 2 batches * TSEQ */
#define MPAD 4224   /* row capacity of activation buffers (33*128) */

__device__ __forceinline__ float bf2f(u16 u) {
  unsigned x = ((unsigned)u) << 16;
  return __builtin_bit_cast(float, x);
}
__device__ __forceinline__ u16 f2bf(float f) {
  unsigned u = __builtin_bit_cast(unsigned, f);
  u += 0x7fffu + ((u >> 16) & 1u);     // round-to-nearest-even
  return (u16)(u >> 16);
}

// async 16B global->LDS (linear dest = wave-uniform base + lane*16)
__device__ __forceinline__ void gll16(const u16* g, u16* l) {
  __builtin_amdgcn_global_load_lds((const __attribute__((address_space(1))) void*)g,
                                   (__attribute__((address_space(3))) void*)l, 16, 0, 0);
}
// XOR swizzle within a 64-element (128B) row: spreads 8 rows over 8 16B slots
__device__ __forceinline__ int swz(int row, int col) {
  return row * 64 + (col ^ ((row & 7) << 3));
}

// ---------------- weight transpose + f32->bf16 cast: (L,K,N) -> (L,N,K) ----
__global__ __launch_bounds__(256) void transpose_w(const float* __restrict__ src,
                                                   u16* __restrict__ dst,
                                                   int K, int N)
{
  __shared__ float tile[32][33];
  const int l = blockIdx.z;
  src += (size_t)l * K * N;
  dst += (size_t)l * K * N;
  const int n0 = blockIdx.x * 32, k0 = blockIdx.y * 32;
  const int c = threadIdx.x & 31, r = threadIdx.x >> 5;
#pragma unroll
  for (int rr = r; rr < 32; rr += 8)
    tile[rr][c] = src[(size_t)(k0 + rr) * N + n0 + c];
  __syncthreads();
#pragma unroll
  for (int rr = r; rr < 32; rr += 8)
    dst[(size_t)(n0 + rr) * K + k0 + c] = f2bf(tile[c][rr]);
}

// ---------------- assemble working sequence with relay tokens --------------
__global__ void build_x(const float* __restrict__ xin, const float* __restrict__ relay,
                        float* __restrict__ xw)
{
  const int total = 2 * TSEQ * 512;
  for (int idx = blockIdx.x * 256 + threadIdx.x; idx < total; idx += gridDim.x * 256) {
    int col = idx & 511;
    int tok = (idx >> 9) % TSEQ;
    int b   = idx / (TSEQ * 512);
    int g = tok / 129, s = tok % 129;
    float v = (s == 0) ? relay[col]
                       : xin[((size_t)b * 2048 + g * 128 + (s - 1)) * 512 + col];
    xw[idx] = v;
  }
}

__global__ void extract_out(const float* __restrict__ xw, float* __restrict__ out)
{
  const int total = 2 * 2048 * 512;
  for (int idx = blockIdx.x * 256 + threadIdx.x; idx < total; idx += gridDim.x * 256) {
    int col = idx & 511;
    int tok = (idx >> 9) & 2047;
    int b   = idx / (2048 * 512);
    int g = tok >> 7, s = tok & 127;
    out[idx] = xw[((size_t)b * TSEQ + g * 129 + s + 1) * 512 + col];
  }
}

// ---------------- layernorm: f32 in -> bf16 out ----------------------------
__global__ __launch_bounds__(256) void ln_kernel(const float* __restrict__ x,
                                                 const float* __restrict__ g,
                                                 const float* __restrict__ bta,
                                                 u16* __restrict__ y, int M)
{
  const int wid = threadIdx.x >> 6, lane = threadIdx.x & 63;
  const int row = blockIdx.x * 4 + wid;
  if (row >= M) return;
  const float* xr = x + (size_t)row * 512;
  float v[8];
  float s = 0.f;
#pragma unroll
  for (int j = 0; j < 8; ++j) { v[j] = xr[j * 64 + lane]; s += v[j]; }
#pragma unroll
  for (int m = 1; m <= 32; m <<= 1) s += __shfl_xor(s, m);
  float mean = s * (1.f / 512.f);
  float vs = 0.f;
#pragma unroll
  for (int j = 0; j < 8; ++j) { float d = v[j] - mean; vs += d * d; }
#pragma unroll
  for (int m = 1; m <= 32; m <<= 1) vs += __shfl_xor(vs, m);
  float rstd = rsqrtf(vs * (1.f / 512.f) + 1e-5f);
  u16* yr = y + (size_t)row * 512;
#pragma unroll
  for (int j = 0; j < 8; ++j) {
    int c = j * 64 + lane;
    yr[c] = f2bf((v[j] - mean) * rstd * g[c] + bta[c]);
  }
}

// ---------------- bf16 MFMA GEMM v2: gll16 + dbuf + swizzle ----------------
// C = A(MxK) * Bt(NxK)^T. 128x128 tile, BK=64, 4 waves (2x2), 64x64/wave.
// A buffers must have >= blockIdx-covered rows allocated (MPAD); N%128==0, K%64==0.
template<bool HAS_BIAS, bool ACT, bool RESID, bool OUT_BF16>
__global__ __launch_bounds__(256) void gemm2(
    const u16* __restrict__ A, const u16* __restrict__ Bt,
    const float* __restrict__ bias, const float* __restrict__ resid,
    void* __restrict__ outp, int M, int N, int K)
{
  __shared__ __attribute__((aligned(16))) u16 As[2][128 * 64];
  __shared__ __attribute__((aligned(16))) u16 Bs[2][128 * 64];
  const int tid = threadIdx.x, lane = tid & 63, wid = tid >> 6;
  const int row0 = blockIdx.x * 128, col0 = blockIdx.y * 128;
  const int wm = (wid >> 1) * 64, wn = (wid & 1) * 64;
  const int srow = tid >> 3, sseg = tid & 7;
  f32x4 acc[4][4];
#pragma unroll
  for (int m = 0; m < 4; ++m)
#pragma unroll
    for (int n = 0; n < 4; ++n) acc[m][n] = (f32x4)0.f;
  const u16* Ab = A + (size_t)row0 * K;
  const u16* Bb = Bt + (size_t)col0 * K;
#pragma unroll
  for (int i = 0; i < 4; ++i) {
    int row = srow + i * 32, ss = sseg ^ (row & 7);
    gll16(Ab + (size_t)row * K + ss * 8, &As[0][row * 64 + sseg * 8]);
    gll16(Bb + (size_t)row * K + ss * 8, &Bs[0][row * 64 + sseg * 8]);
  }
  const int fr = lane & 15, g = lane >> 4;
  int cur = 0;
  for (int k0 = 0; k0 < K; k0 += 64) {
    __syncthreads();                       // buf[cur] ready (drains gll queue)
    if (k0 + 64 < K) {
      u16* ad = &As[cur ^ 1][0];
      u16* bd = &Bs[cur ^ 1][0];
#pragma unroll
      for (int i = 0; i < 4; ++i) {
        int row = srow + i * 32, ss = sseg ^ (row & 7);
        gll16(Ab + (size_t)row * K + k0 + 64 + ss * 8, ad + row * 64 + sseg * 8);
        gll16(Bb + (size_t)row * K + k0 + 64 + ss * 8, bd + row * 64 + sseg * 8);
      }
    }
    const u16* as_ = &As[cur][0];
    const u16* bs_ = &Bs[cur][0];
    bf16x8 a[2][4], bb[2][4];
#pragma unroll
    for (int kk = 0; kk < 2; ++kk) {
#pragma unroll
      for (int m = 0; m < 4; ++m) a[kk][m] = *(const bf16x8*)&as_[swz(wm + m * 16 + fr, kk * 32 + g * 8)];
#pragma unroll
      for (int n = 0; n < 4; ++n) bb[kk][n] = *(const bf16x8*)&bs_[swz(wn + n * 16 + fr, kk * 32 + g * 8)];
    }
    __builtin_amdgcn_s_setprio(1);
#pragma unroll
    for (int kk = 0; kk < 2; ++kk)
#pragma unroll
      for (int m = 0; m < 4; ++m)
#pragma unroll
        for (int n = 0; n < 4; ++n)
          acc[m][n] = __builtin_amdgcn_mfma_f32_16x16x32_bf16(a[kk][m], bb[kk][n], acc[m][n], 0, 0, 0);
    __builtin_amdgcn_s_setprio(0);
    cur ^= 1;
  }

  const int fg = lane >> 4;
#pragma unroll
  for (int m = 0; m < 4; ++m) {
#pragma unroll
    for (int n = 0; n < 4; ++n) {
#pragma unroll
      for (int j = 0; j < 4; ++j) {
        int grow = row0 + wm + m * 16 + fg * 4 + j;
        int gcol = col0 + wn + n * 16 + fr;
        if (grow < M) {
          float v = acc[m][n][j];
          if (HAS_BIAS) v += bias[gcol];
          if (ACT) v = (v > 0.f) ? v : 0.01f * v;
          if (RESID) v += resid[(size_t)grow * N + gcol];
          if (OUT_BF16) ((u16*)outp)[(size_t)grow * N + gcol] = f2bf(v);
          else ((float*)outp)[(size_t)grow * N + gcol] = v;
        }
      }
    }
  }
}

// ---------------- V transpose: big V-part -> vg[bh][64 d][2112 tok] --------
__global__ __launch_bounds__(256) void vtrans(const u16* __restrict__ big,
                                              u16* __restrict__ vg)
{
  __shared__ u16 t[64][72];
  const int tt = blockIdx.x;        // token tile 0..32
  const int bh = blockIdx.y;        // b*8+h
  const int b = bh >> 3, h = bh & 7;
  const int tid = threadIdx.x;
  const int srow = tid >> 3, sseg = tid & 7;
  const int t0 = tt * 64;
#pragma unroll
  for (int i = 0; i < 2; ++i) {
    int row = srow + i * 32;        // token within tile (may be OOB -> garbage, masked later)
    u16x8 v = *(const u16x8*)&big[((size_t)(b * TSEQ) + t0 + row) * 1536 + 1024 + h * 64 + sseg * 8];
    *(u16x8*)&t[row][sseg * 8] = v;
  }
  __syncthreads();
#pragma unroll
  for (int i = 0; i < 2; ++i) {
    int d = srow + i * 32;
    u16x8 v;
#pragma unroll
    for (int j = 0; j < 8; ++j) v[j] = t[sseg * 8 + j][d];
    *(u16x8*)&vg[((size_t)bh * 64 + d) * 2112 + t0 + sseg * 8] = v;
  }
}

// ---------------- flash attention v2: swizzled LDS, gll16, dbuf KV ---------
// grid (33, 16); block 256 = 4 waves; BQ=64 (16 q-rows/wave), BKV=64.
__global__ __launch_bounds__(256) void flash_attn2(const u16* __restrict__ big,
                                                   const u16* __restrict__ vg,
                                                   u16* __restrict__ ob)
{
  __shared__ __attribute__((aligned(16))) u16 Qs[64 * 64];
  __shared__ __attribute__((aligned(16))) u16 Ks[2][64 * 64];
  __shared__ __attribute__((aligned(16))) u16 Vs[2][64 * 64];
  __shared__ __attribute__((aligned(16))) u16 Ps[4][16 * 64];
  const int tid = threadIdx.x, lane = tid & 63, wid = tid >> 6;
  const int qt = blockIdx.x, b = blockIdx.y >> 3, h = blockIdx.y & 7;
  const int q0 = qt * 64;
  const int srow = tid >> 3, sseg = tid & 7;

  const u16* qb = big + ((size_t)(b * TSEQ) + q0) * 1536 + h * 64;
  const u16* kb = big + ((size_t)(b * TSEQ)) * 1536 + h * 64 + 512;
  const u16* vb = vg + (size_t)blockIdx.y * 64 * 2112;
#pragma unroll
  for (int i = 0; i < 2; ++i) {
    int row = srow + i * 32, ss = sseg ^ (row & 7);
    gll16(qb + (size_t)row * 1536 + ss * 8, &Qs[row * 64 + sseg * 8]);
    gll16(kb + (size_t)row * 1536 + ss * 8, &Ks[0][row * 64 + sseg * 8]);
    gll16(vb + (size_t)row * 2112 + ss * 8, &Vs[0][row * 64 + sseg * 8]);
  }
  __syncthreads();
  const int fr = lane & 15, g = lane >> 4;
  bf16x8 aq0 = *(const bf16x8*)&Qs[swz(wid * 16 + fr, g * 8)];
  bf16x8 aq1 = *(const bf16x8*)&Qs[swz(wid * 16 + fr, 32 + g * 8)];

  f32x4 oacc[4];
#pragma unroll
  for (int nf = 0; nf < 4; ++nf) oacc[nf] = (f32x4)0.f;
  float mrow[4] = {-1e30f, -1e30f, -1e30f, -1e30f};
  float lsum[4] = {0.f, 0.f, 0.f, 0.f};
  int cur = 0;

  for (int kt = 0; kt < 33; ++kt) {
    if (kt + 1 < 33) {                       // prefetch next tile into buf^1
      const u16* kb2 = kb + (size_t)(kt + 1) * 64 * 1536;
      const u16* vb2 = vb + (kt + 1) * 64;
      u16* kd = &Ks[cur ^ 1][0];
      u16* vd = &Vs[cur ^ 1][0];
#pragma unroll
      for (int i = 0; i < 2; ++i) {
        int row = srow + i * 32, ss = sseg ^ (row & 7);
        gll16(kb2 + (size_t)row * 1536 + ss * 8, kd + row * 64 + sseg * 8);
        gll16(vb2 + (size_t)row * 2112 + ss * 8, vd + row * 64 + sseg * 8);
      }
    }
    const u16* ks = &Ks[cur][0];
    const u16* vs = &Vs[cur][0];
    f32x4 s[4];
    __builtin_amdgcn_s_setprio(1);
#pragma unroll
    for (int n = 0; n < 4; ++n) {
      int row = n * 16 + fr;
      bf16x8 bk0 = *(const bf16x8*)&ks[swz(row, g * 8)];
      bf16x8 bk1 = *(const bf16x8*)&ks[swz(row, 32 + g * 8)];
      f32x4 t = (f32x4)0.f;
      t = __builtin_amdgcn_mfma_f32_16x16x32_bf16(aq0, bk0, t, 0, 0, 0);
      t = __builtin_amdgcn_mfma_f32_16x16x32_bf16(aq1, bk1, t, 0, 0, 0);
      s[n] = t;
    }
    __builtin_amdgcn_s_setprio(0);
#pragma unroll
    for (int n = 0; n < 4; ++n) {
      bool valid = (kt * 64 + n * 16 + fr) < TSEQ;
#pragma unroll
      for (int j = 0; j < 4; ++j) s[n][j] = valid ? s[n][j] * 0.125f : -1e30f;
    }
    float sc[4];
#pragma unroll
    for (int j = 0; j < 4; ++j) {
      float m0 = fmaxf(fmaxf(s[0][j], s[1][j]), fmaxf(s[2][j], s[3][j]));
#pragma unroll
      for (int d = 1; d <= 8; d <<= 1) m0 = fmaxf(m0, __shfl_xor(m0, d));
      float nm = fmaxf(mrow[j], m0);
      sc[j] = __expf(mrow[j] - nm);
      mrow[j] = nm;
      lsum[j] *= sc[j];
    }
#pragma unroll
    for (int nf = 0; nf < 4; ++nf)
#pragma unroll
      for (int j = 0; j < 4; ++j) oacc[nf][j] *= sc[j];

    float ps[4] = {0.f, 0.f, 0.f, 0.f};
#pragma unroll
    for (int n = 0; n < 4; ++n) {
#pragma unroll
      for (int j = 0; j < 4; ++j) {
        float p = __expf(s[n][j] - mrow[j]);
        ps[j] += p;
        Ps[wid][swz(g * 4 + j, n * 16 + fr)] = f2bf(p);
      }
    }
#pragma unroll
    for (int j = 0; j < 4; ++j) {
      float t = ps[j];
#pragma unroll
      for (int d = 1; d <= 8; d <<= 1) t += __shfl_xor(t, d);
      lsum[j] += t;
    }
    __builtin_amdgcn_s_setprio(1);
#pragma unroll
    for (int kc = 0; kc < 2; ++kc) {
      bf16x8 ap = *(const bf16x8*)&Ps[wid][swz(fr, kc * 32 + g * 8)];
#pragma unroll
      for (int nf = 0; nf < 4; ++nf) {
        bf16x8 bv = *(const bf16x8*)&vs[swz(nf * 16 + fr, kc * 32 + g * 8)];
        oacc[nf] = __builtin_amdgcn_mfma_f32_16x16x32_bf16(ap, bv, oacc[nf], 0, 0, 0);
      }
    }
    __builtin_amdgcn_s_setprio(0);
    __syncthreads();                         // next tile ready; readers done
    cur ^= 1;
  }

  float inv[4];
#pragma unroll
  for (int j = 0; j < 4; ++j) inv[j] = 1.f / lsum[j];
#pragma unroll
  for (int nf = 0; nf < 4; ++nf) {
#pragma unroll
    for (int j = 0; j < 4; ++j) {
      int row = q0 + wid * 16 + g * 4 + j;
      if (row < TSEQ)
        ob[((size_t)(b * TSEQ + row)) * 512 + h * 64 + nf * 16 + fr] = f2bf(oacc[nf][j] * inv[j]);
    }
  }
}

// ---------------- relay-token global attention (32 tokens total) -----------
__global__ __launch_bounds__(256) void global_attn(const u16* __restrict__ rqkv,
                                                   u16* __restrict__ ro)
{
  const int b = blockIdx.x >> 3, h = blockIdx.x & 7;
  __shared__ float q[16][64], k[16][64], v[16][64], s[16][16], p[16][16];
  const int tid = threadIdx.x;
  for (int idx = tid; idx < 1024; idx += 256) {
    int rr = idx >> 6, c = idx & 63;
    size_t base = (size_t)(b * 16 + rr) * 1536 + h * 64 + c;
    q[rr][c] = bf2f(rqkv[base]);
    k[rr][c] = bf2f(rqkv[base + 512]);
    v[rr][c] = bf2f(rqkv[base + 1024]);
  }
  __syncthreads();
  {
    int i = tid >> 4, j = tid & 15;
    float acc = 0.f;
#pragma unroll
    for (int d = 0; d < 64; ++d) acc += q[i][d] * k[j][d];
    s[i][j] = acc * 0.125f;
  }
  __syncthreads();
  if (tid < 16) {
    float mx = -1e30f;
#pragma unroll
    for (int j = 0; j < 16; ++j) mx = fmaxf(mx, s[tid][j]);
    float sum = 0.f;
#pragma unroll
    for (int j = 0; j < 16; ++j) { float e = __expf(s[tid][j] - mx); p[tid][j] = e; sum += e; }
    float iv = 1.f / sum;
#pragma unroll
    for (int j = 0; j < 16; ++j) p[tid][j] *= iv;
  }
  __syncthreads();
  for (int idx = tid; idx < 1024; idx += 256) {
    int rr = idx >> 6, c = idx & 63;
    float acc = 0.f;
#pragma unroll
    for (int j = 0; j < 16; ++j) acc += p[rr][j] * v[j][c];
    ro[(size_t)(b * 16 + rr) * 512 + h * 64 + c] = f2bf(acc);
  }
}

__global__ void gather_relay(const u16* __restrict__ y, u16* __restrict__ rbuf)
{
  int idx = blockIdx.x * 256 + threadIdx.x;   // 32*512
  int col = idx & 511, rr = idx >> 9;
  int b = rr >> 4, g = rr & 15;
  rbuf[idx] = y[((size_t)b * TSEQ + g * 129) * 512 + col];
}

__global__ void relay_scatter(const float* __restrict__ rout, const u16* __restrict__ rbuf,
                              u16* __restrict__ y)
{
  int idx = blockIdx.x * 256 + threadIdx.x;   // 32*512
  int col = idx & 511, rr = idx >> 9;
  int b = rr >> 4, g = rr & 15;
  y[((size_t)b * TSEQ + g * 129) * 512 + col] = f2bf(rout[idx] + bf2f(rbuf[idx]));
}

// ---------------------------------------------------------------------------
extern "C" void kernel_launch(void* const* d_in, const int* in_sizes, int n_in,
                              void* d_out, int out_size, void* d_ws, size_t ws_size,
                              hipStream_t stream)
{
  const float* x_in     = (const float*)d_in[0];
  const float* rel_emb  = (const float*)d_in[1];
  const float* ln1_g    = (const float*)d_in[2];
  const float* ln1_b    = (const float*)d_in[3];
  const float* loc_qkv  = (const float*)d_in[4];
  const float* loc_ow   = (const float*)d_in[5];
  const float* loc_ob   = (const float*)d_in[6];
  const float* glob_qkv = (const float*)d_in[7];
  const float* glob_ow  = (const float*)d_in[8];
  const float* glob_ob  = (const float*)d_in[9];
  const float* ln2_g    = (const float*)d_in[10];
  const float* ln2_b    = (const float*)d_in[11];
  const float* ff_w1    = (const float*)d_in[12];
  const float* ff_b1    = (const float*)d_in[13];
  const float* ff_w2    = (const float*)d_in[14];
  const float* ff_b2    = (const float*)d_in[15];

  char* ws = (char*)d_ws;
  float* xbuf = (float*)(ws + 0);              // f32 [MPAD][512]   8,650,752
  u16*   ybuf = (u16*)(ws + 8650752);          // bf16 [MPAD][512]  4,325,376
  u16*   obuf = (u16*)(ws + 12976128);         // bf16 [MPAD][512]  4,325,376
  u16*   big  = (u16*)(ws + 17301504);         // bf16 [MPAD][2048] 17,301,504
  u16*   vg   = (u16*)(ws + 34603008);         // bf16 [16*64][2112] 4,325,376
  u16*   wLQ  = (u16*)(ws + 38928384);         // 4x1536x512  6,291,456
  u16*   wGQ  = (u16*)(ws + 45219840);         // 6,291,456
  u16*   wLO  = (u16*)(ws + 51511296);         // 4x512x512   2,097,152
  u16*   wGO  = (u16*)(ws + 53608448);         // 2,097,152
  u16*   wF1  = (u16*)(ws + 55705600);         // 4x2048x512  8,388,608
  u16*   wF2  = (u16*)(ws + 64094208);         // 4x512x2048  8,388,608
  u16*   rbuf = (u16*)(ws + 72482816);         // [128][512] bf16 (32 valid rows) 131,072
  u16*   rqkv = (u16*)(ws + 72613888);         // 32x1536     98,304
  u16*   rov  = (u16*)(ws + 72712192);         // [128][512] bf16 131,072
  float* rout = (float*)(ws + 72843264);       // 32x512 f32  65,536

  dim3 B(256);
  transpose_w<<<dim3(48, 16, 4), B, 0, stream>>>(loc_qkv, wLQ, 512, 1536);
  transpose_w<<<dim3(48, 16, 4), B, 0, stream>>>(glob_qkv, wGQ, 512, 1536);
  transpose_w<<<dim3(16, 16, 4), B, 0, stream>>>(loc_ow, wLO, 512, 512);
  transpose_w<<<dim3(16, 16, 4), B, 0, stream>>>(glob_ow, wGO, 512, 512);
  transpose_w<<<dim3(64, 16, 4), B, 0, stream>>>(ff_w1, wF1, 512, 2048);
  transpose_w<<<dim3(16, 64, 4), B, 0, stream>>>(ff_w2, wF2, 2048, 512);

  build_x<<<8256, B, 0, stream>>>(x_in, rel_emb, xbuf);

  for (int l = 0; l < 4; ++l) {
    ln_kernel<<<1032, B, 0, stream>>>(xbuf, ln1_g + l * 512, ln1_b + l * 512, ybuf, NTOK);
    if (l + 1 >= 2) {
      gather_relay<<<64, B, 0, stream>>>(ybuf, rbuf);
      gemm2<false, false, false, true><<<dim3(1, 12), B, 0, stream>>>(
          rbuf, wGQ + (size_t)l * 1536 * 512, nullptr, nullptr, rqkv, 32, 1536, 512);
      global_attn<<<16, B, 0, stream>>>(rqkv, rov);
      gemm2<true, false, false, false><<<dim3(1, 4), B, 0, stream>>>(
          rov, wGO + (size_t)l * 512 * 512, glob_ob + l * 512, nullptr, rout, 32, 512, 512);
      relay_scatter<<<64, B, 0, stream>>>(rout, rbuf, ybuf);
    }
    gemm2<false, false, false, true><<<dim3(33, 12), B, 0, stream>>>(
        ybuf, wLQ + (size_t)l * 1536 * 512, nullptr, nullptr, big, NTOK, 1536, 512);
    vtrans<<<dim3(33, 16), B, 0, stream>>>(big, vg);
    flash_attn2<<<dim3(33, 16), B, 0, stream>>>(big, vg, obuf);
    gemm2<true, false, true, false><<<dim3(33, 4), B, 0, stream>>>(
        obuf, wLO + (size_t)l * 512 * 512, loc_ob + l * 512, xbuf, xbuf, NTOK, 512, 512);
    ln_kernel<<<1032, B, 0, stream>>>(xbuf, ln2_g + l * 512, ln2_b + l * 512, ybuf, NTOK);
    gemm2<true, true, false, true><<<dim3(33, 16), B, 0, stream>>>(
        ybuf, wF1 + (size_t)l * 2048 * 512, ff_b1 + l * 2048, nullptr, big, NTOK, 2048, 512);
    gemm2<true, false, true, false><<<dim3(33, 4), B, 0, stream>>>(
        big, wF2 + (size_t)l * 512 * 2048, ff_b2 + l * 512, xbuf, xbuf, NTOK, 512, 2048);
  }
  extract_out<<<8192, B, 0, stream>>>(xbuf, (float*)d_out);
}

// Round 4
// 1071.133 us; speedup vs baseline: 1.3229x; 1.0829x over previous
//
#include <hip/hip_runtime.h>

typedef __attribute__((ext_vector_type(8))) __bf16 bf16x8;
typedef __attribute__((ext_vector_type(8))) unsigned short u16x8;
typedef __attribute__((ext_vector_type(4))) unsigned short u16x4;
typedef __attribute__((ext_vector_type(4))) float f32x4;
typedef unsigned short u16;

#define TSEQ 2064   /* 16 groups * 129 tokens (incl relay) per batch */
#define NTOK 4128   /* 2 batches * TSEQ */
#define MPAD 4224   /* row capacity of activation buffers (33*128) */

__device__ __forceinline__ float bf2f(u16 u) {
  unsigned x = ((unsigned)u) << 16;
  return __builtin_bit_cast(float, x);
}
__device__ __forceinline__ u16 f2bf(float f) {
  unsigned u = __builtin_bit_cast(unsigned, f);
  u += 0x7fffu + ((u >> 16) & 1u);     // round-to-nearest-even
  return (u16)(u >> 16);
}

// async 16B global->LDS (linear dest = wave-uniform base + lane*16)
__device__ __forceinline__ void gll16(const u16* g, u16* l) {
  __builtin_amdgcn_global_load_lds((const __attribute__((address_space(1))) void*)g,
                                   (__attribute__((address_space(3))) void*)l, 16, 0, 0);
}
// XOR swizzle within a 64-element (128B) row: spreads 8 rows over 8 16B slots
__device__ __forceinline__ int swz(int row, int col) {
  return row * 64 + (col ^ ((row & 7) << 3));
}

// ---------------- weight transpose + f32->bf16 cast: (L,K,N) -> (L,N,K) ----
__global__ __launch_bounds__(256) void transpose_w(const float* __restrict__ src,
                                                   u16* __restrict__ dst,
                                                   int K, int N)
{
  __shared__ float tile[32][33];
  const int l = blockIdx.z;
  src += (size_t)l * K * N;
  dst += (size_t)l * K * N;
  const int n0 = blockIdx.x * 32, k0 = blockIdx.y * 32;
  const int c = threadIdx.x & 31, r = threadIdx.x >> 5;
#pragma unroll
  for (int rr = r; rr < 32; rr += 8)
    tile[rr][c] = src[(size_t)(k0 + rr) * N + n0 + c];
  __syncthreads();
#pragma unroll
  for (int rr = r; rr < 32; rr += 8)
    dst[(size_t)(n0 + rr) * K + k0 + c] = f2bf(tile[c][rr]);
}

// ---------------- assemble working sequence with relay tokens --------------
__global__ void build_x(const float* __restrict__ xin, const float* __restrict__ relay,
                        float* __restrict__ xw)
{
  const int total = 2 * TSEQ * 512;
  for (int idx = blockIdx.x * 256 + threadIdx.x; idx < total; idx += gridDim.x * 256) {
    int col = idx & 511;
    int tok = (idx >> 9) % TSEQ;
    int b   = idx / (TSEQ * 512);
    int g = tok / 129, s = tok % 129;
    float v = (s == 0) ? relay[col]
                       : xin[((size_t)b * 2048 + g * 128 + (s - 1)) * 512 + col];
    xw[idx] = v;
  }
}

__global__ void extract_out(const float* __restrict__ xw, float* __restrict__ out)
{
  const int total = 2 * 2048 * 512;
  for (int idx = blockIdx.x * 256 + threadIdx.x; idx < total; idx += gridDim.x * 256) {
    int col = idx & 511;
    int tok = (idx >> 9) & 2047;
    int b   = idx / (2048 * 512);
    int g = tok >> 7, s = tok & 127;
    out[idx] = xw[((size_t)b * TSEQ + g * 129 + s + 1) * 512 + col];
  }
}

// ---------------- layernorm: f32 in -> bf16 out ----------------------------
__global__ __launch_bounds__(256) void ln_kernel(const float* __restrict__ x,
                                                 const float* __restrict__ g,
                                                 const float* __restrict__ bta,
                                                 u16* __restrict__ y, int M)
{
  const int wid = threadIdx.x >> 6, lane = threadIdx.x & 63;
  const int row = blockIdx.x * 4 + wid;
  if (row >= M) return;
  const float* xr = x + (size_t)row * 512;
  float v[8];
  float s = 0.f;
#pragma unroll
  for (int j = 0; j < 8; ++j) { v[j] = xr[j * 64 + lane]; s += v[j]; }
#pragma unroll
  for (int m = 1; m <= 32; m <<= 1) s += __shfl_xor(s, m);
  float mean = s * (1.f / 512.f);
  float vs = 0.f;
#pragma unroll
  for (int j = 0; j < 8; ++j) { float d = v[j] - mean; vs += d * d; }
#pragma unroll
  for (int m = 1; m <= 32; m <<= 1) vs += __shfl_xor(vs, m);
  float rstd = rsqrtf(vs * (1.f / 512.f) + 1e-5f);
  u16* yr = y + (size_t)row * 512;
#pragma unroll
  for (int j = 0; j < 8; ++j) {
    int c = j * 64 + lane;
    yr[c] = f2bf((v[j] - mean) * rstd * g[c] + bta[c]);
  }
}

// ---------------- bf16 MFMA GEMM: gll16 + dbuf + swizzle -------------------
// C = A(MxK) * Bt(NxK)^T. 128x128 tile, BK=64, 4 waves (2x2), 64x64/wave.
// VOUT: QKV gemm fuses the V transpose (cols>=1024 -> vg[bh*64+d][tok]).
template<bool HAS_BIAS, bool ACT, bool RESID, bool OUT_BF16, bool VOUT>
__global__ __launch_bounds__(256) void gemm2(
    const u16* __restrict__ A, const u16* __restrict__ Bt,
    const float* __restrict__ bias, const float* __restrict__ resid,
    void* __restrict__ outp, u16* __restrict__ vgout, int M, int N, int K)
{
  __shared__ __attribute__((aligned(16))) u16 As[2][128 * 64];
  __shared__ __attribute__((aligned(16))) u16 Bs[2][128 * 64];
  const int tid = threadIdx.x, lane = tid & 63, wid = tid >> 6;
  const int row0 = blockIdx.x * 128, col0 = blockIdx.y * 128;
  const int wm = (wid >> 1) * 64, wn = (wid & 1) * 64;
  const int srow = tid >> 3, sseg = tid & 7;
  f32x4 acc[4][4];
#pragma unroll
  for (int m = 0; m < 4; ++m)
#pragma unroll
    for (int n = 0; n < 4; ++n) acc[m][n] = (f32x4)0.f;
  const u16* Ab = A + (size_t)row0 * K;
  const u16* Bb = Bt + (size_t)col0 * K;
#pragma unroll
  for (int i = 0; i < 4; ++i) {
    int row = srow + i * 32, ss = sseg ^ (row & 7);
    gll16(Ab + (size_t)row * K + ss * 8, &As[0][row * 64 + sseg * 8]);
    gll16(Bb + (size_t)row * K + ss * 8, &Bs[0][row * 64 + sseg * 8]);
  }
  const int fr = lane & 15, g = lane >> 4;
  int cur = 0;
  for (int k0 = 0; k0 < K; k0 += 64) {
    __syncthreads();                       // buf[cur] ready (drains gll queue)
    if (k0 + 64 < K) {
      u16* ad = &As[cur ^ 1][0];
      u16* bd = &Bs[cur ^ 1][0];
#pragma unroll
      for (int i = 0; i < 4; ++i) {
        int row = srow + i * 32, ss = sseg ^ (row & 7);
        gll16(Ab + (size_t)row * K + k0 + 64 + ss * 8, ad + row * 64 + sseg * 8);
        gll16(Bb + (size_t)row * K + k0 + 64 + ss * 8, bd + row * 64 + sseg * 8);
      }
    }
    const u16* as_ = &As[cur][0];
    const u16* bs_ = &Bs[cur][0];
    bf16x8 a[2][4], bb[2][4];
#pragma unroll
    for (int kk = 0; kk < 2; ++kk) {
#pragma unroll
      for (int m = 0; m < 4; ++m) a[kk][m] = *(const bf16x8*)&as_[swz(wm + m * 16 + fr, kk * 32 + g * 8)];
#pragma unroll
      for (int n = 0; n < 4; ++n) bb[kk][n] = *(const bf16x8*)&bs_[swz(wn + n * 16 + fr, kk * 32 + g * 8)];
    }
    __builtin_amdgcn_s_setprio(1);
#pragma unroll
    for (int kk = 0; kk < 2; ++kk)
#pragma unroll
      for (int m = 0; m < 4; ++m)
#pragma unroll
        for (int n = 0; n < 4; ++n)
          acc[m][n] = __builtin_amdgcn_mfma_f32_16x16x32_bf16(a[kk][m], bb[kk][n], acc[m][n], 0, 0, 0);
    __builtin_amdgcn_s_setprio(0);
    cur ^= 1;
  }

#pragma unroll
  for (int m = 0; m < 4; ++m) {
#pragma unroll
    for (int n = 0; n < 4; ++n) {
#pragma unroll
      for (int j = 0; j < 4; ++j) {
        int grow = row0 + wm + m * 16 + g * 4 + j;
        int gcol = col0 + wn + n * 16 + fr;
        if (grow < M) {
          float v = acc[m][n][j];
          if (HAS_BIAS) v += bias[gcol];
          if (ACT) v = (v > 0.f) ? v : 0.01f * v;
          if (RESID) v += resid[(size_t)grow * N + gcol];
          if (VOUT && gcol >= 1024) {          // V region -> transposed vg only
            int hh = (gcol - 1024) >> 6, dd = gcol & 63;
            int bb2 = grow >= TSEQ;
            int tok = grow - bb2 * TSEQ;
            vgout[((size_t)((bb2 * 8 + hh) * 64 + dd)) * 2112 + tok] = f2bf(v);
          } else if (OUT_BF16) {
            ((u16*)outp)[(size_t)grow * N + gcol] = f2bf(v);
          } else {
            ((float*)outp)[(size_t)grow * N + gcol] = v;
          }
        }
      }
    }
  }
}

// ---------------- flash attention v3: swapped QK^T, KV-split, partials -----
// grid (33 q-tiles, 16 bh, 2 kv-halves); block 256 = 4 waves; BQ=64, BKV=64.
// Writes unnormalized O partial (bf16) + (m,l) per row; fa_combine merges.
__global__ __launch_bounds__(256) void flash_attn3(const u16* __restrict__ big,
                                                   const u16* __restrict__ vg,
                                                   u16* __restrict__ op0,
                                                   u16* __restrict__ op1,
                                                   float2* __restrict__ mlb)
{
  __shared__ __attribute__((aligned(16))) u16 Qs[64 * 64];   // Q, then per-wave P
  __shared__ __attribute__((aligned(16))) u16 Ks[2][64 * 64];
  __shared__ __attribute__((aligned(16))) u16 Vs[2][64 * 64];
  const int tid = threadIdx.x, lane = tid & 63, wid = tid >> 6;
  const int qt = blockIdx.x, bh = blockIdx.y, z = blockIdx.z;
  const int b = bh >> 3, h = bh & 7;
  const int q0 = qt * 64;
  const int srow = tid >> 3, sseg = tid & 7;
  const int ktbeg = z * 17, ktend = z ? 33 : 17;

  const u16* qb = big + ((size_t)(b * TSEQ) + q0) * 1536 + h * 64;
  const u16* kb = big + ((size_t)(b * TSEQ)) * 1536 + h * 64 + 512;
  const u16* vb = vg + (size_t)bh * 64 * 2112;
#pragma unroll
  for (int i = 0; i < 2; ++i) {
    int row = srow + i * 32, ss = sseg ^ (row & 7);
    gll16(qb + (size_t)row * 1536 + ss * 8, &Qs[row * 64 + sseg * 8]);
    gll16(kb + (size_t)(ktbeg * 64 + row) * 1536 + ss * 8, &Ks[0][row * 64 + sseg * 8]);
    gll16(vb + (size_t)row * 2112 + ktbeg * 64 + ss * 8, &Vs[0][row * 64 + sseg * 8]);
  }
  __syncthreads();
  const int fr = lane & 15, g = lane >> 4;
  // Q fragments to registers (B-operand for swapped QK^T); Qs bytes of this
  // wave's rows are then reused as the wave-private P scratch.
  bf16x8 aq0 = *(const bf16x8*)&Qs[swz(wid * 16 + fr, g * 8)];
  bf16x8 aq1 = *(const bf16x8*)&Qs[swz(wid * 16 + fr, 32 + g * 8)];
  u16* Pw = &Qs[wid * 1024];

  f32x4 oacc[4];
#pragma unroll
  for (int nf = 0; nf < 4; ++nf) oacc[nf] = (f32x4)0.f;
  float mrow = -1e30f, lsum = 0.f;   // stats for q-row = fr (replicated over g)
  int cur = 0;

  for (int kt = ktbeg; kt < ktend; ++kt) {
    if (kt + 1 < ktend) {                    // prefetch next tile into buf^1
      const u16* kb2 = kb + (size_t)(kt + 1) * 64 * 1536;
      const u16* vb2 = vb + (kt + 1) * 64;
      u16* kd = &Ks[cur ^ 1][0];
      u16* vd = &Vs[cur ^ 1][0];
#pragma unroll
      for (int i = 0; i < 2; ++i) {
        int row = srow + i * 32, ss = sseg ^ (row & 7);
        gll16(kb2 + (size_t)row * 1536 + ss * 8, kd + row * 64 + sseg * 8);
        gll16(vb2 + (size_t)row * 2112 + ss * 8, vd + row * 64 + sseg * 8);
      }
    }
    const u16* ks = &Ks[cur][0];
    const u16* vs = &Vs[cur][0];
    // S^T = K * Q^T : lane holds S[q=fr][k = kt*64 + n*16 + g*4 + j]
    f32x4 s[4];
    __builtin_amdgcn_s_setprio(1);
#pragma unroll
    for (int n = 0; n < 4; ++n) {
      int row = n * 16 + fr;
      bf16x8 ak0 = *(const bf16x8*)&ks[swz(row, g * 8)];
      bf16x8 ak1 = *(const bf16x8*)&ks[swz(row, 32 + g * 8)];
      f32x4 t = (f32x4)0.f;
      t = __builtin_amdgcn_mfma_f32_16x16x32_bf16(ak0, aq0, t, 0, 0, 0);
      t = __builtin_amdgcn_mfma_f32_16x16x32_bf16(ak1, aq1, t, 0, 0, 0);
      s[n] = t;
    }
    __builtin_amdgcn_s_setprio(0);
#pragma unroll
    for (int n = 0; n < 4; ++n) {
      int kbase = kt * 64 + n * 16 + g * 4;
#pragma unroll
      for (int j = 0; j < 4; ++j)
        s[n][j] = (kbase + j < TSEQ) ? s[n][j] * 0.125f : -1e30f;
    }
    // row max: 15 local + 2 shfl
    float mloc = s[0][0];
#pragma unroll
    for (int n = 0; n < 4; ++n)
#pragma unroll
      for (int j = 0; j < 4; ++j) mloc = fmaxf(mloc, s[n][j]);
    mloc = fmaxf(mloc, __shfl_xor(mloc, 16));
    mloc = fmaxf(mloc, __shfl_xor(mloc, 32));
    float nm = fmaxf(mrow, mloc);
    float sc = __expf(mrow - nm);
    mrow = nm;
    lsum *= sc;
    // p = exp(s - nm); packed b64 stores into wave-private P
    float psum = 0.f;
#pragma unroll
    for (int n = 0; n < 4; ++n) {
      u16x4 pw;
#pragma unroll
      for (int j = 0; j < 4; ++j) {
        float p = __expf(s[n][j] - nm);
        psum += p;
        pw[j] = f2bf(p);
      }
      *(u16x4*)&Pw[swz(fr, n * 16 + g * 4)] = pw;
    }
    psum += __shfl_xor(psum, 16);
    psum += __shfl_xor(psum, 32);
    lsum += psum;
    // rescale O (rows q = g*4+j; fetch that row's sc from lane g*4+j)
    float s4[4];
#pragma unroll
    for (int j = 0; j < 4; ++j) s4[j] = __shfl(sc, g * 4 + j);
#pragma unroll
    for (int nf = 0; nf < 4; ++nf)
#pragma unroll
      for (int j = 0; j < 4; ++j) oacc[nf][j] *= s4[j];
    // PV
    __builtin_amdgcn_s_setprio(1);
#pragma unroll
    for (int kc = 0; kc < 2; ++kc) {
      bf16x8 ap = *(const bf16x8*)&Pw[swz(fr, kc * 32 + g * 8)];
#pragma unroll
      for (int nf = 0; nf < 4; ++nf) {
        bf16x8 bv = *(const bf16x8*)&vs[swz(nf * 16 + fr, kc * 32 + g * 8)];
        oacc[nf] = __builtin_amdgcn_mfma_f32_16x16x32_bf16(ap, bv, oacc[nf], 0, 0, 0);
      }
    }
    __builtin_amdgcn_s_setprio(0);
    __syncthreads();                         // next tile ready; readers done
    cur ^= 1;
  }

  u16* op = z ? op1 : op0;
#pragma unroll
  for (int nf = 0; nf < 4; ++nf) {
#pragma unroll
    for (int j = 0; j < 4; ++j) {
      int row = q0 + wid * 16 + g * 4 + j;
      if (row < TSEQ)
        op[((size_t)(b * TSEQ + row)) * 512 + h * 64 + nf * 16 + fr] = f2bf(oacc[nf][j]);
    }
  }
  if (lane < 16) {
    int row = q0 + wid * 16 + fr;
    if (row < TSEQ)
      mlb[(size_t)(z * 16 + bh) * 2112 + row] = float2{mrow, lsum};
  }
}

// ---------------- merge the two KV-half partials ---------------------------
__global__ __launch_bounds__(256) void fa_combine(const u16* __restrict__ op0,
                                                  const u16* __restrict__ op1,
                                                  const float2* __restrict__ mlb,
                                                  u16* __restrict__ ob)
{
  int idx = blockIdx.x * 256 + threadIdx.x;   // NTOK*128 threads, 4 cols each
  int tok = idx >> 7;
  int c4 = (idx & 127) * 4;
  int b = tok >= TSEQ;
  int row = tok - b * TSEQ;
  int h = c4 >> 6;
  float2 ml0 = mlb[(size_t)(b * 8 + h) * 2112 + row];
  float2 ml1 = mlb[(size_t)(16 + b * 8 + h) * 2112 + row];
  float M = fmaxf(ml0.x, ml1.x);
  float a0 = __expf(ml0.x - M), a1 = __expf(ml1.x - M);
  float inv = 1.f / (ml0.y * a0 + ml1.y * a1);
  u16x4 v0 = *(const u16x4*)&op0[(size_t)tok * 512 + c4];
  u16x4 v1 = *(const u16x4*)&op1[(size_t)tok * 512 + c4];
  u16x4 o;
#pragma unroll
  for (int j = 0; j < 4; ++j)
    o[j] = f2bf((bf2f(v0[j]) * a0 + bf2f(v1[j]) * a1) * inv);
  *(u16x4*)&ob[(size_t)tok * 512 + c4] = o;
}

// ---------------- relay-token global attention (32 tokens total) -----------
__global__ __launch_bounds__(256) void global_attn(const u16* __restrict__ rqkv,
                                                   u16* __restrict__ ro)
{
  const int b = blockIdx.x >> 3, h = blockIdx.x & 7;
  __shared__ float q[16][64], k[16][64], v[16][64], s[16][16], p[16][16];
  const int tid = threadIdx.x;
  for (int idx = tid; idx < 1024; idx += 256) {
    int rr = idx >> 6, c = idx & 63;
    size_t base = (size_t)(b * 16 + rr) * 1536 + h * 64 + c;
    q[rr][c] = bf2f(rqkv[base]);
    k[rr][c] = bf2f(rqkv[base + 512]);
    v[rr][c] = bf2f(rqkv[base + 1024]);
  }
  __syncthreads();
  {
    int i = tid >> 4, j = tid & 15;
    float acc = 0.f;
#pragma unroll
    for (int d = 0; d < 64; ++d) acc += q[i][d] * k[j][d];
    s[i][j] = acc * 0.125f;
  }
  __syncthreads();
  if (tid < 16) {
    float mx = -1e30f;
#pragma unroll
    for (int j = 0; j < 16; ++j) mx = fmaxf(mx, s[tid][j]);
    float sum = 0.f;
#pragma unroll
    for (int j = 0; j < 16; ++j) { float e = __expf(s[tid][j] - mx); p[tid][j] = e; sum += e; }
    float iv = 1.f / sum;
#pragma unroll
    for (int j = 0; j < 16; ++j) p[tid][j] *= iv;
  }
  __syncthreads();
  for (int idx = tid; idx < 1024; idx += 256) {
    int rr = idx >> 6, c = idx & 63;
    float acc = 0.f;
#pragma unroll
    for (int j = 0; j < 16; ++j) acc += p[rr][j] * v[j][c];
    ro[(size_t)(b * 16 + rr) * 512 + h * 64 + c] = f2bf(acc);
  }
}

__global__ void gather_relay(const u16* __restrict__ y, u16* __restrict__ rbuf)
{
  int idx = blockIdx.x * 256 + threadIdx.x;   // 32*512
  int col = idx & 511, rr = idx >> 9;
  int b = rr >> 4, g = rr & 15;
  rbuf[idx] = y[((size_t)b * TSEQ + g * 129) * 512 + col];
}

__global__ void relay_scatter(const float* __restrict__ rout, const u16* __restrict__ rbuf,
                              u16* __restrict__ y)
{
  int idx = blockIdx.x * 256 + threadIdx.x;   // 32*512
  int col = idx & 511, rr = idx >> 9;
  int b = rr >> 4, g = rr & 15;
  y[((size_t)b * TSEQ + g * 129) * 512 + col] = f2bf(rout[idx] + bf2f(rbuf[idx]));
}

// ---------------------------------------------------------------------------
extern "C" void kernel_launch(void* const* d_in, const int* in_sizes, int n_in,
                              void* d_out, int out_size, void* d_ws, size_t ws_size,
                              hipStream_t stream)
{
  const float* x_in     = (const float*)d_in[0];
  const float* rel_emb  = (const float*)d_in[1];
  const float* ln1_g    = (const float*)d_in[2];
  const float* ln1_b    = (const float*)d_in[3];
  const float* loc_qkv  = (const float*)d_in[4];
  const float* loc_ow   = (const float*)d_in[5];
  const float* loc_ob   = (const float*)d_in[6];
  const float* glob_qkv = (const float*)d_in[7];
  const float* glob_ow  = (const float*)d_in[8];
  const float* glob_ob  = (const float*)d_in[9];
  const float* ln2_g    = (const float*)d_in[10];
  const float* ln2_b    = (const float*)d_in[11];
  const float* ff_w1    = (const float*)d_in[12];
  const float* ff_b1    = (const float*)d_in[13];
  const float* ff_w2    = (const float*)d_in[14];
  const float* ff_b2    = (const float*)d_in[15];

  char* ws = (char*)d_ws;
  float* xbuf = (float*)(ws + 0);              // f32 [MPAD][512]   8,650,752
  u16*   ybuf = (u16*)(ws + 8650752);          // bf16 [MPAD][512]  (LN out; flash O-partial half0)
  u16*   obuf = (u16*)(ws + 12976128);         // bf16 [MPAD][512]  (flash O-partial half1 + combine out)
  u16*   big  = (u16*)(ws + 17301504);         // bf16 [MPAD][2048] 17,301,504
  u16*   vg   = (u16*)(ws + 34603008);         // bf16 [16*64][2112] 4,325,376
  u16*   wLQ  = (u16*)(ws + 38928384);         // 4x1536x512  6,291,456
  u16*   wGQ  = (u16*)(ws + 45219840);         // 6,291,456
  u16*   wLO  = (u16*)(ws + 51511296);         // 4x512x512   2,097,152
  u16*   wGO  = (u16*)(ws + 53608448);         // 2,097,152
  u16*   wF1  = (u16*)(ws + 55705600);         // 4x2048x512  8,388,608
  u16*   wF2  = (u16*)(ws + 64094208);         // 4x512x2048  8,388,608
  u16*   rbuf = (u16*)(ws + 72482816);         // [128][512] bf16 131,072
  u16*   rqkv = (u16*)(ws + 72613888);         // 32x1536     98,304
  u16*   rov  = (u16*)(ws + 72712192);         // [128][512] bf16 131,072
  float* rout = (float*)(ws + 72843264);       // 32x512 f32  65,536
  float2* mlb = (float2*)(ws + 72908800);      // [2][16][2112] float2 540,672 (end 73,449,472)

  dim3 B(256);
  transpose_w<<<dim3(48, 16, 4), B, 0, stream>>>(loc_qkv, wLQ, 512, 1536);
  transpose_w<<<dim3(48, 16, 4), B, 0, stream>>>(glob_qkv, wGQ, 512, 1536);
  transpose_w<<<dim3(16, 16, 4), B, 0, stream>>>(loc_ow, wLO, 512, 512);
  transpose_w<<<dim3(16, 16, 4), B, 0, stream>>>(glob_ow, wGO, 512, 512);
  transpose_w<<<dim3(64, 16, 4), B, 0, stream>>>(ff_w1, wF1, 512, 2048);
  transpose_w<<<dim3(16, 64, 4), B, 0, stream>>>(ff_w2, wF2, 2048, 512);

  build_x<<<8256, B, 0, stream>>>(x_in, rel_emb, xbuf);

  for (int l = 0; l < 4; ++l) {
    ln_kernel<<<1032, B, 0, stream>>>(xbuf, ln1_g + l * 512, ln1_b + l * 512, ybuf, NTOK);
    if (l + 1 >= 2) {
      gather_relay<<<64, B, 0, stream>>>(ybuf, rbuf);
      gemm2<false, false, false, true, false><<<dim3(1, 12), B, 0, stream>>>(
          rbuf, wGQ + (size_t)l * 1536 * 512, nullptr, nullptr, rqkv, nullptr, 32, 1536, 512);
      global_attn<<<16, B, 0, stream>>>(rqkv, rov);
      gemm2<true, false, false, false, false><<<dim3(1, 4), B, 0, stream>>>(
          rov, wGO + (size_t)l * 512 * 512, glob_ob + l * 512, nullptr, rout, nullptr, 32, 512, 512);
      relay_scatter<<<64, B, 0, stream>>>(rout, rbuf, ybuf);
    }
    gemm2<false, false, false, true, true><<<dim3(33, 12), B, 0, stream>>>(
        ybuf, wLQ + (size_t)l * 1536 * 512, nullptr, nullptr, big, vg, NTOK, 1536, 512);
    flash_attn3<<<dim3(33, 16, 2), B, 0, stream>>>(big, vg, ybuf, obuf, mlb);
    fa_combine<<<2064, B, 0, stream>>>(ybuf, obuf, mlb, obuf);
    gemm2<true, false, true, false, false><<<dim3(33, 4), B, 0, stream>>>(
        obuf, wLO + (size_t)l * 512 * 512, loc_ob + l * 512, xbuf, xbuf, nullptr, NTOK, 512, 512);
    ln_kernel<<<1032, B, 0, stream>>>(xbuf, ln2_g + l * 512, ln2_b + l * 512, ybuf, NTOK);
    gemm2<true, true, false, true, false><<<dim3(33, 16), B, 0, stream>>>(
        ybuf, wF1 + (size_t)l * 2048 * 512, ff_b1 + l * 2048, nullptr, big, nullptr, NTOK, 2048, 512);
    gemm2<true, false, true, false, false><<<dim3(33, 4), B, 0, stream>>>(
        big, wF2 + (size_t)l * 512 * 2048, ff_b2 + l * 512, xbuf, xbuf, nullptr, NTOK, 512, 2048);
  }
  extract_out<<<8192, B, 0, stream>>>(xbuf, (float*)d_out);
}

// Round 5
// 931.880 us; speedup vs baseline: 1.5206x; 1.1494x over previous
//
#include <hip/hip_runtime.h>

typedef __attribute__((ext_vector_type(8))) __bf16 bf16x8;
typedef __attribute__((ext_vector_type(8))) unsigned short u16x8;
typedef __attribute__((ext_vector_type(4))) unsigned short u16x4;
typedef __attribute__((ext_vector_type(2))) unsigned int u32x2;
typedef __attribute__((ext_vector_type(4))) float f32x4;
typedef unsigned short u16;
typedef unsigned int u32;

#define TSEQ 2064   /* 16 groups * 129 tokens (incl relay) per batch */
#define NTOK 4128   /* 2 batches * TSEQ */

__device__ __forceinline__ float bf2f(u16 u) {
  unsigned x = ((unsigned)u) << 16;
  return __builtin_bit_cast(float, x);
}
__device__ __forceinline__ u16 f2bf(float f) {
  unsigned u = __builtin_bit_cast(unsigned, f);
  u += 0x7fffu + ((u >> 16) & 1u);     // round-to-nearest-even
  return (u16)(u >> 16);
}

// async 16B global->LDS (linear dest = wave-uniform base + lane*16)
__device__ __forceinline__ void gll16(const u16* g, u16* l) {
  __builtin_amdgcn_global_load_lds((const __attribute__((address_space(1))) void*)g,
                                   (__attribute__((address_space(3))) void*)l, 16, 0, 0);
}
// XOR swizzle within a 64-element (128B) row: spreads 8 rows over 8 16B slots
__device__ __forceinline__ int swz(int row, int col) {
  return row * 64 + (col ^ ((row & 7) << 3));
}

// ---------------- all weight transposes in ONE launch ----------------------
// (L,K,N) -> (L,N,K), f32 -> bf16
__global__ __launch_bounds__(256) void transpose_all(
    const float* __restrict__ s0, const float* __restrict__ s1,
    const float* __restrict__ s2, const float* __restrict__ s3,
    const float* __restrict__ s4, const float* __restrict__ s5,
    u16* __restrict__ d0, u16* __restrict__ d1, u16* __restrict__ d2,
    u16* __restrict__ d3, u16* __restrict__ d4, u16* __restrict__ d5)
{
  __shared__ float tile[32][33];
  int bid = blockIdx.x;
  const float* src; u16* dst; int K, N, r;
  if (bid < 6144)       { int w = bid >> 11 >= 1 && bid >= 3072; r = bid - (bid >= 3072 ? 3072 : 0);
                          K = 512; N = 1536; src = bid >= 3072 ? s1 : s0; dst = bid >= 3072 ? d1 : d0; }
  else if (bid < 8192)  { r = bid - (bid >= 7168 ? 7168 : 6144);
                          K = 512; N = 512;  src = bid >= 7168 ? s3 : s2; dst = bid >= 7168 ? d3 : d2; }
  else if (bid < 12288) { r = bid - 8192;  K = 512;  N = 2048; src = s4; dst = d4; }
  else                  { r = bid - 12288; K = 2048; N = 512;  src = s5; dst = d5; }
  const int tx = N >> 5, per = tx * (K >> 5);
  const int l = r / per; r -= l * per;
  const int n0 = (r % tx) * 32, k0 = (r / tx) * 32;
  src += (size_t)l * K * N;
  dst += (size_t)l * K * N;
  const int c = threadIdx.x & 31, rr0 = threadIdx.x >> 5;
#pragma unroll
  for (int rr = rr0; rr < 32; rr += 8)
    tile[rr][c] = src[(size_t)(k0 + rr) * N + n0 + c];
  __syncthreads();
#pragma unroll
  for (int rr = rr0; rr < 32; rr += 8)
    dst[(size_t)(n0 + rr) * K + k0 + c] = f2bf(tile[c][rr]);
}

// ---------------- assemble working sequence with relay tokens --------------
__global__ void build_x(const float* __restrict__ xin, const float* __restrict__ relay,
                        float* __restrict__ xw)
{
  const int total = 2 * TSEQ * 512;
  for (int idx = blockIdx.x * 256 + threadIdx.x; idx < total; idx += gridDim.x * 256) {
    int col = idx & 511;
    int tok = (idx >> 9) % TSEQ;
    int b   = idx / (TSEQ * 512);
    int g = tok / 129, s = tok % 129;
    float v = (s == 0) ? relay[col]
                       : xin[((size_t)b * 2048 + g * 128 + (s - 1)) * 512 + col];
    xw[idx] = v;
  }
}

__global__ void extract_out(const float* __restrict__ xw, float* __restrict__ out)
{
  const int total = 2 * 2048 * 512;
  for (int idx = blockIdx.x * 256 + threadIdx.x; idx < total; idx += gridDim.x * 256) {
    int col = idx & 511;
    int tok = (idx >> 9) & 2047;
    int b   = idx / (2048 * 512);
    int g = tok >> 7, s = tok & 127;
    out[idx] = xw[((size_t)b * TSEQ + g * 129 + s + 1) * 512 + col];
  }
}

// ---------------- layernorm: f32 in -> bf16 out ----------------------------
__global__ __launch_bounds__(256) void ln_kernel(const float* __restrict__ x,
                                                 const float* __restrict__ g,
                                                 const float* __restrict__ bta,
                                                 u16* __restrict__ y, int M)
{
  const int wid = threadIdx.x >> 6, lane = threadIdx.x & 63;
  const int row = blockIdx.x * 4 + wid;
  if (row >= M) return;
  const float* xr = x + (size_t)row * 512;
  float v[8];
  float s = 0.f;
#pragma unroll
  for (int j = 0; j < 8; ++j) { v[j] = xr[j * 64 + lane]; s += v[j]; }
#pragma unroll
  for (int m = 1; m <= 32; m <<= 1) s += __shfl_xor(s, m);
  float mean = s * (1.f / 512.f);
  float vs = 0.f;
#pragma unroll
  for (int j = 0; j < 8; ++j) { float d = v[j] - mean; vs += d * d; }
#pragma unroll
  for (int m = 1; m <= 32; m <<= 1) vs += __shfl_xor(vs, m);
  float rstd = rsqrtf(vs * (1.f / 512.f) + 1e-5f);
  u16* yr = y + (size_t)row * 512;
#pragma unroll
  for (int j = 0; j < 8; ++j) {
    int c = j * 64 + lane;
    yr[c] = f2bf((v[j] - mean) * rstd * g[c] + bta[c]);
  }
}

__device__ __forceinline__ int relay_tok(int r) {   // r in 0..31 -> token index
  return (r >> 4) * TSEQ + (r & 15) * 129;
}

// ---------------- bf16 MFMA GEMM v3: single-buffer 32KB, 4 blocks/CU -------
// C = A(MxK) * Bt(NxK)^T. 128x128 tile, BK=64, 4 waves (2x2), 64x64/wave.
// VOUT: QKV gemm -> V cols transposed to vg, Q cols pre-scaled by 0.125.
// RELAYA: A rows remapped to relay tokens of ybuf. RELAYC: out += into ybuf
// at relay token positions (fused residual + scatter).
template<bool HAS_BIAS, bool ACT, bool RESID, bool OUT_BF16, bool VOUT,
         bool RELAYA, bool RELAYC>
__global__ __launch_bounds__(256, 4) void gemm3(
    const u16* __restrict__ A, const u16* __restrict__ Bt,
    const float* __restrict__ bias, const float* __restrict__ resid,
    void* __restrict__ outp, u16* __restrict__ vgout, int M, int N, int K)
{
  __shared__ __attribute__((aligned(16))) u16 As[128 * 64];
  __shared__ __attribute__((aligned(16))) u16 Bs[128 * 64];
  const int tid = threadIdx.x, lane = tid & 63, wid = tid >> 6;
  const int row0 = blockIdx.x * 128, col0 = blockIdx.y * 128;
  const int wm = (wid >> 1) * 64, wn = (wid & 1) * 64;
  const int srow = tid >> 3, sseg = tid & 7;
  f32x4 acc[4][4];
#pragma unroll
  for (int m = 0; m < 4; ++m)
#pragma unroll
    for (int n = 0; n < 4; ++n) acc[m][n] = (f32x4)0.f;
  const u16* Bb = Bt + (size_t)col0 * K;
  const int fr = lane & 15, g = lane >> 4;

  for (int k0 = 0; k0 < K; k0 += 64) {
    __syncthreads();                       // previous step's readers done
#pragma unroll
    for (int i = 0; i < 4; ++i) {
      int row = srow + i * 32, ss = sseg ^ (row & 7);
      size_t arow = RELAYA ? (size_t)relay_tok(row & 31) : (size_t)(row0 + row);
      gll16(A + arow * K + k0 + ss * 8, &As[row * 64 + sseg * 8]);
      gll16(Bb + (size_t)row * K + k0 + ss * 8, &Bs[row * 64 + sseg * 8]);
    }
    __syncthreads();                       // drain gll queue
#pragma unroll
    for (int kk = 0; kk < 2; ++kk) {
      bf16x8 a[4], bb[4];
#pragma unroll
      for (int m = 0; m < 4; ++m) a[m] = *(const bf16x8*)&As[swz(wm + m * 16 + fr, kk * 32 + g * 8)];
#pragma unroll
      for (int n = 0; n < 4; ++n) bb[n] = *(const bf16x8*)&Bs[swz(wn + n * 16 + fr, kk * 32 + g * 8)];
      __builtin_amdgcn_s_setprio(1);
#pragma unroll
      for (int m = 0; m < 4; ++m)
#pragma unroll
        for (int n = 0; n < 4; ++n)
          acc[m][n] = __builtin_amdgcn_mfma_f32_16x16x32_bf16(a[m], bb[n], acc[m][n], 0, 0, 0);
      __builtin_amdgcn_s_setprio(0);
    }
  }

#pragma unroll
  for (int m = 0; m < 4; ++m) {
#pragma unroll
    for (int n = 0; n < 4; ++n) {
#pragma unroll
      for (int j = 0; j < 4; ++j) {
        int grow = row0 + wm + m * 16 + g * 4 + j;
        int gcol = col0 + wn + n * 16 + fr;
        if (grow < M) {
          float v = acc[m][n][j];
          if (HAS_BIAS) v += bias[gcol];
          if (ACT) v = (v > 0.f) ? v : 0.01f * v;
          if (RESID) v += resid[(size_t)grow * N + gcol];
          if (RELAYC) {                        // fused residual+scatter to ybuf
            u16* p = (u16*)outp + (size_t)relay_tok(grow) * 512 + gcol;
            *p = f2bf(v + bf2f(*p));
          } else if (VOUT && gcol >= 1024) {   // V region -> transposed vg only
            int hh = (gcol - 1024) >> 6, dd = gcol & 63;
            int bb2 = grow >= TSEQ;
            int tok = grow - bb2 * TSEQ;
            vgout[((size_t)((bb2 * 8 + hh) * 64 + dd)) * 2112 + tok] = f2bf(v);
          } else if (OUT_BF16) {
            if (VOUT && gcol < 512) v *= 0.125f;   // pre-scale Q for attention
            ((u16*)outp)[(size_t)grow * N + gcol] = f2bf(v);
          } else {
            ((float*)outp)[(size_t)grow * N + gcol] = v;
          }
        }
      }
    }
  }
}

// ---------------- flash attention v4: BQ=128, 8 waves, defer-max -----------
// grid (17 q-tiles, 16 bh, 2 kv-halves); block 512 = 8 waves.
// Q pre-scaled by 0.125 in QKV epilogue. Writes unnormalized O partial (bf16)
// + (m,l) per row; fa_combine merges the two halves.
__global__ __launch_bounds__(512, 4) void flash_attn4(const u16* __restrict__ big,
                                                      const u16* __restrict__ vg,
                                                      u16* __restrict__ op0,
                                                      u16* __restrict__ op1,
                                                      float2* __restrict__ mlb)
{
  __shared__ __attribute__((aligned(16))) u16 Qs[128 * 64];  // Q, then 8x P-scratch
  __shared__ __attribute__((aligned(16))) u16 Ks[2][64 * 64];
  __shared__ __attribute__((aligned(16))) u16 Vs[2][64 * 64];
  const int tid = threadIdx.x, lane = tid & 63, wid = tid >> 6;
  const int qt = blockIdx.x, bh = blockIdx.y, z = blockIdx.z;
  const int b = bh >> 3, h = bh & 7;
  const int q0 = qt * 128;
  const int srow = tid >> 3, sseg = tid & 7;
  const int ktbeg = z * 17, ktend = z ? 33 : 17;

  const u16* kb = big + ((size_t)(b * TSEQ)) * 1536 + h * 64 + 512;
  const u16* vb = vg + (size_t)bh * 64 * 2112;
#pragma unroll
  for (int i = 0; i < 2; ++i) {
    int row = srow + i * 64;
    int grow = b * TSEQ + q0 + row; grow = grow < NTOK ? grow : NTOK - 1;
    int ss = sseg ^ (row & 7);
    gll16(big + (size_t)grow * 1536 + h * 64 + ss * 8, &Qs[row * 64 + sseg * 8]);
  }
  {
    int ss = sseg ^ (srow & 7);
    gll16(kb + (size_t)(ktbeg * 64 + srow) * 1536 + ss * 8, &Ks[0][srow * 64 + sseg * 8]);
    gll16(vb + (size_t)srow * 2112 + ktbeg * 64 + ss * 8, &Vs[0][srow * 64 + sseg * 8]);
  }
  __syncthreads();
  const int fr = lane & 15, g = lane >> 4;
  bf16x8 aq0 = *(const bf16x8*)&Qs[swz(wid * 16 + fr, g * 8)];
  bf16x8 aq1 = *(const bf16x8*)&Qs[swz(wid * 16 + fr, 32 + g * 8)];
  u16* Pw = &Qs[wid * 1024];   // wave-private 16x64 P scratch (overlays Q)

  f32x4 oacc[4];
#pragma unroll
  for (int nf = 0; nf < 4; ++nf) oacc[nf] = (f32x4)0.f;
  float mrow = -1e30f, lsum = 0.f;   // stats for q-row = fr (replicated over g)
  int cur = 0;

  for (int kt = ktbeg; kt < ktend; ++kt) {
    if (kt + 1 < ktend) {                    // prefetch next tile into buf^1
      int ss = sseg ^ (srow & 7);
      gll16(kb + (size_t)((kt + 1) * 64 + srow) * 1536 + ss * 8, &Ks[cur ^ 1][srow * 64 + sseg * 8]);
      gll16(vb + (size_t)srow * 2112 + (kt + 1) * 64 + ss * 8, &Vs[cur ^ 1][srow * 64 + sseg * 8]);
    }
    const u16* ks = &Ks[cur][0];
    const u16* vs = &Vs[cur][0];
    // S^T = K * Q^T : lane holds S[k = kt*64 + n*16 + g*4 + j][q = fr]
    f32x4 s[4];
    __builtin_amdgcn_s_setprio(1);
#pragma unroll
    for (int n = 0; n < 4; ++n) {
      int row = n * 16 + fr;
      bf16x8 ak0 = *(const bf16x8*)&ks[swz(row, g * 8)];
      bf16x8 ak1 = *(const bf16x8*)&ks[swz(row, 32 + g * 8)];
      f32x4 t = (f32x4)0.f;
      t = __builtin_amdgcn_mfma_f32_16x16x32_bf16(ak0, aq0, t, 0, 0, 0);
      t = __builtin_amdgcn_mfma_f32_16x16x32_bf16(ak1, aq1, t, 0, 0, 0);
      s[n] = t;
    }
    __builtin_amdgcn_s_setprio(0);
    if (kt == 32) {                          // only ragged tile needs masking
#pragma unroll
      for (int n = 0; n < 4; ++n) {
        int kbase = kt * 64 + n * 16 + g * 4;
#pragma unroll
        for (int j = 0; j < 4; ++j)
          if (kbase + j >= TSEQ) s[n][j] = -1e30f;
      }
    }
    // row max: 15 local + 2 shfl (replica-uniform per q-row)
    float mloc = s[0][0];
#pragma unroll
    for (int n = 0; n < 4; ++n)
#pragma unroll
      for (int j = 0; j < 4; ++j) mloc = fmaxf(mloc, s[n][j]);
    mloc = fmaxf(mloc, __shfl_xor(mloc, 16));
    mloc = fmaxf(mloc, __shfl_xor(mloc, 32));
    if (!__all(mloc <= mrow + 8.f)) {        // defer-max: rescale only on growth
      float nm = fmaxf(mrow, mloc);
      float sc = __expf(mrow - nm);
      mrow = nm;
      lsum *= sc;
      float s4[4];
#pragma unroll
      for (int j = 0; j < 4; ++j) s4[j] = __shfl(sc, g * 4 + j);
#pragma unroll
      for (int nf = 0; nf < 4; ++nf)
#pragma unroll
        for (int j = 0; j < 4; ++j) oacc[nf][j] *= s4[j];
    }
    // p = exp(s - mrow); truncation-pack pairs via v_perm
    float psum = 0.f;
#pragma unroll
    for (int n = 0; n < 4; ++n) {
      float p0 = __expf(s[n][0] - mrow), p1 = __expf(s[n][1] - mrow);
      float p2 = __expf(s[n][2] - mrow), p3 = __expf(s[n][3] - mrow);
      psum += (p0 + p1) + (p2 + p3);
      u32x2 pk;
      pk[0] = __builtin_amdgcn_perm(__builtin_bit_cast(u32, p1), __builtin_bit_cast(u32, p0), 0x07060302u);
      pk[1] = __builtin_amdgcn_perm(__builtin_bit_cast(u32, p3), __builtin_bit_cast(u32, p2), 0x07060302u);
      *(u32x2*)&Pw[swz(fr, n * 16 + g * 4)] = pk;
    }
    psum += __shfl_xor(psum, 16);
    psum += __shfl_xor(psum, 32);
    lsum += psum;
    // PV
    __builtin_amdgcn_s_setprio(1);
#pragma unroll
    for (int kc = 0; kc < 2; ++kc) {
      bf16x8 ap = *(const bf16x8*)&Pw[swz(fr, kc * 32 + g * 8)];
#pragma unroll
      for (int nf = 0; nf < 4; ++nf) {
        bf16x8 bv = *(const bf16x8*)&vs[swz(nf * 16 + fr, kc * 32 + g * 8)];
        oacc[nf] = __builtin_amdgcn_mfma_f32_16x16x32_bf16(ap, bv, oacc[nf], 0, 0, 0);
      }
    }
    __builtin_amdgcn_s_setprio(0);
    __syncthreads();                         // next tile staged; readers done
    cur ^= 1;
  }

  u16* op = z ? op1 : op0;
#pragma unroll
  for (int nf = 0; nf < 4; ++nf) {
#pragma unroll
    for (int j = 0; j < 4; ++j) {
      int row = q0 + wid * 16 + g * 4 + j;
      if (row < TSEQ)
        op[((size_t)(b * TSEQ + row)) * 512 + h * 64 + nf * 16 + fr] = f2bf(oacc[nf][j]);
    }
  }
  if (lane < 16) {
    int row = q0 + wid * 16 + fr;
    if (row < TSEQ)
      mlb[(size_t)(z * 16 + bh) * 2112 + row] = float2{mrow, lsum};
  }
}

// ---------------- merge the two KV-half partials ---------------------------
__global__ __launch_bounds__(256) void fa_combine(const u16* __restrict__ op0,
                                                  const u16* __restrict__ op1,
                                                  const float2* __restrict__ mlb,
                                                  u16* __restrict__ ob)
{
  int idx = blockIdx.x * 256 + threadIdx.x;   // NTOK*128 threads, 4 cols each
  int tok = idx >> 7;
  int c4 = (idx & 127) * 4;
  int b = tok >= TSEQ;
  int row = tok - b * TSEQ;
  int h = c4 >> 6;
  float2 ml0 = mlb[(size_t)(b * 8 + h) * 2112 + row];
  float2 ml1 = mlb[(size_t)(16 + b * 8 + h) * 2112 + row];
  float M = fmaxf(ml0.x, ml1.x);
  float a0 = __expf(ml0.x - M), a1 = __expf(ml1.x - M);
  float inv = 1.f / (ml0.y * a0 + ml1.y * a1);
  u16x4 v0 = *(const u16x4*)&op0[(size_t)tok * 512 + c4];
  u16x4 v1 = *(const u16x4*)&op1[(size_t)tok * 512 + c4];
  u16x4 o;
#pragma unroll
  for (int j = 0; j < 4; ++j)
    o[j] = f2bf((bf2f(v0[j]) * a0 + bf2f(v1[j]) * a1) * inv);
  *(u16x4*)&ob[(size_t)tok * 512 + c4] = o;
}

// ---------------- relay-token global attention (32 tokens total) -----------
__global__ __launch_bounds__(256) void global_attn(const u16* __restrict__ rqkv,
                                                   u16* __restrict__ ro)
{
  const int b = blockIdx.x >> 3, h = blockIdx.x & 7;
  __shared__ float q[16][64], k[16][64], v[16][64], s[16][16], p[16][16];
  const int tid = threadIdx.x;
  for (int idx = tid; idx < 1024; idx += 256) {
    int rr = idx >> 6, c = idx & 63;
    size_t base = (size_t)(b * 16 + rr) * 1536 + h * 64 + c;
    q[rr][c] = bf2f(rqkv[base]);
    k[rr][c] = bf2f(rqkv[base + 512]);
    v[rr][c] = bf2f(rqkv[base + 1024]);
  }
  __syncthreads();
  {
    int i = tid >> 4, j = tid & 15;
    float acc = 0.f;
#pragma unroll
    for (int d = 0; d < 64; ++d) acc += q[i][d] * k[j][d];
    s[i][j] = acc * 0.125f;
  }
  __syncthreads();
  if (tid < 16) {
    float mx = -1e30f;
#pragma unroll
    for (int j = 0; j < 16; ++j) mx = fmaxf(mx, s[tid][j]);
    float sum = 0.f;
#pragma unroll
    for (int j = 0; j < 16; ++j) { float e = __expf(s[tid][j] - mx); p[tid][j] = e; sum += e; }
    float iv = 1.f / sum;
#pragma unroll
    for (int j = 0; j < 16; ++j) p[tid][j] *= iv;
  }
  __syncthreads();
  for (int idx = tid; idx < 1024; idx += 256) {
    int rr = idx >> 6, c = idx & 63;
    float acc = 0.f;
#pragma unroll
    for (int j = 0; j < 16; ++j) acc += p[rr][j] * v[j][c];
    ro[(size_t)(b * 16 + rr) * 512 + h * 64 + c] = f2bf(acc);
  }
}

// ---------------------------------------------------------------------------
extern "C" void kernel_launch(void* const* d_in, const int* in_sizes, int n_in,
                              void* d_out, int out_size, void* d_ws, size_t ws_size,
                              hipStream_t stream)
{
  const float* x_in     = (const float*)d_in[0];
  const float* rel_emb  = (const float*)d_in[1];
  const float* ln1_g    = (const float*)d_in[2];
  const float* ln1_b    = (const float*)d_in[3];
  const float* loc_qkv  = (const float*)d_in[4];
  const float* loc_ow   = (const float*)d_in[5];
  const float* loc_ob   = (const float*)d_in[6];
  const float* glob_qkv = (const float*)d_in[7];
  const float* glob_ow  = (const float*)d_in[8];
  const float* glob_ob  = (const float*)d_in[9];
  const float* ln2_g    = (const float*)d_in[10];
  const float* ln2_b    = (const float*)d_in[11];
  const float* ff_w1    = (const float*)d_in[12];
  const float* ff_b1    = (const float*)d_in[13];
  const float* ff_w2    = (const float*)d_in[14];
  const float* ff_b2    = (const float*)d_in[15];

  char* ws = (char*)d_ws;
  float*  xbuf = (float*)(ws + 0);             // f32 [4224][512]   8,650,752
  u16*    ybuf = (u16*)(ws + 8650752);         // bf16 [4224][512]  (LN out; flash O-partial 0)
  u16*    obuf = (u16*)(ws + 12976128);        // bf16 [4224][512]  (flash O-partial 1 / combined)
  u16*    big  = (u16*)(ws + 17301504);        // bf16 [4224][2048] 17,301,504
  u16*    vg   = (u16*)(ws + 34603008);        // bf16 [16*64][2112] 4,325,376
  u16*    wLQ  = (u16*)(ws + 38928384);        // 4x1536x512  6,291,456
  u16*    wGQ  = (u16*)(ws + 45219840);        // 6,291,456
  u16*    wLO  = (u16*)(ws + 51511296);        // 4x512x512   2,097,152
  u16*    wGO  = (u16*)(ws + 53608448);        // 2,097,152
  u16*    wF1  = (u16*)(ws + 55705600);        // 4x2048x512  8,388,608
  u16*    wF2  = (u16*)(ws + 64094208);        // 4x512x2048  8,388,608
  u16*    rqkv = (u16*)(ws + 72482816);        // 32x1536     98,304
  u16*    rov  = (u16*)(ws + 72581120);        // [128][512] bf16 131,072
  float2* mlb  = (float2*)(ws + 72712192);     // [2][16][2112] float2 540,672 (end 73,252,864)

  dim3 B(256);
  transpose_all<<<16384, B, 0, stream>>>(loc_qkv, glob_qkv, loc_ow, glob_ow, ff_w1, ff_w2,
                                         wLQ, wGQ, wLO, wGO, wF1, wF2);
  build_x<<<8256, B, 0, stream>>>(x_in, rel_emb, xbuf);

  for (int l = 0; l < 4; ++l) {
    ln_kernel<<<1032, B, 0, stream>>>(xbuf, ln1_g + l * 512, ln1_b + l * 512, ybuf, NTOK);
    if (l + 1 >= 2) {
      gemm3<false, false, false, true, false, true, false><<<dim3(1, 12), B, 0, stream>>>(
          ybuf, wGQ + (size_t)l * 1536 * 512, nullptr, nullptr, rqkv, nullptr, 32, 1536, 512);
      global_attn<<<16, B, 0, stream>>>(rqkv, rov);
      gemm3<true, false, false, true, false, false, true><<<dim3(1, 4), B, 0, stream>>>(
          rov, wGO + (size_t)l * 512 * 512, glob_ob + l * 512, nullptr, ybuf, nullptr, 32, 512, 512);
    }
    gemm3<false, false, false, true, true, false, false><<<dim3(33, 12), B, 0, stream>>>(
        ybuf, wLQ + (size_t)l * 1536 * 512, nullptr, nullptr, big, vg, NTOK, 1536, 512);
    flash_attn4<<<dim3(17, 16, 2), dim3(512), 0, stream>>>(big, vg, ybuf, obuf, mlb);
    fa_combine<<<2064, B, 0, stream>>>(ybuf, obuf, mlb, obuf);
    gemm3<true, false, true, false, false, false, false><<<dim3(33, 4), B, 0, stream>>>(
        obuf, wLO + (size_t)l * 512 * 512, loc_ob + l * 512, xbuf, xbuf, nullptr, NTOK, 512, 512);
    ln_kernel<<<1032, B, 0, stream>>>(xbuf, ln2_g + l * 512, ln2_b + l * 512, ybuf, NTOK);
    gemm3<true, true, false, true, false, false, false><<<dim3(33, 16), B, 0, stream>>>(
        ybuf, wF1 + (size_t)l * 2048 * 512, ff_b1 + l * 2048, nullptr, big, nullptr, NTOK, 2048, 512);
    gemm3<true, false, true, false, false, false, false><<<dim3(33, 4), B, 0, stream>>>(
        big, wF2 + (size_t)l * 512 * 2048, ff_b2 + l * 512, xbuf, xbuf, nullptr, NTOK, 512, 2048);
  }
  extract_out<<<8192, B, 0, stream>>>(xbuf, (float*)d_out);
}